// Round 9
// baseline (4051.861 us; speedup 1.0000x reference)
//
#include <hip/hip_runtime.h>
#include <cstdint>
#include <cstddef>
#include <cmath>

#define NLAYER 6
#define NH 12
#define DMODEL 384
#define DHEAD 32
#define DFFN 1536
#define BATCH 64
#define SEQ 512
#define NROWS (BATCH*SEQ)   // 32768
#define DQKV 1152           // fused q|k|v row length
#define FFN_CHUNK 16384     // 2 chunks; h buffer reused (sequential chunks)
#define PSEG 4              // scan segments (chunk-parallel)
#define TSEG (SEQ/PSEG)     // 128 steps per segment
#define SCAN_T 32
#define SPAD 36

typedef unsigned short ushort;
typedef __attribute__((ext_vector_type(8))) short bf16x8;   // 8 bf16 = 4 VGPRs
typedef __attribute__((ext_vector_type(4))) float f32x4;

// ---------------------------------------------------------------- utilities

__device__ inline float bf2f(ushort u) {
    union { unsigned int i; float f; } c; c.i = ((unsigned int)u) << 16; return c.f;
}
__device__ inline ushort f2bf(float f) {
    union { float f; unsigned int i; } c; c.f = f;
    unsigned int i = c.i;
    unsigned int lsb = (i >> 16) & 1u;
    i += 0x7fffu + lsb;          // round-to-nearest-even
    return (ushort)(i >> 16);
}

__device__ inline float wave_reduce_sum(float v) {
    #pragma unroll
    for (int m = 32; m >= 1; m >>= 1) v += __shfl_xor(v, m, 64);
    return v;
}

__device__ inline float sigmoidf(float x) { return 1.0f / (1.0f + expf(-x)); }

__device__ inline float gelu_tanh(float x) {
    const float c = 0.7978845608028654f; // sqrt(2/pi)
    float t = tanhf(c * (x + 0.044715f * x * x * x));
    return 0.5f * x * (1.0f + t);
}

// async global->LDS, 16 bytes per lane; lds base must be wave-uniform
__device__ inline void async16(const ushort* g, ushort* l) {
    __builtin_amdgcn_global_load_lds(
        (const __attribute__((address_space(1))) unsigned int*)g,
        (__attribute__((address_space(3))) unsigned int*)l,
        16, 0, 0);
}

// dot of two float2[16] register arrays -> scalar (4 chains + tree)
__device__ inline float dot16(const float2* a, const float2* b) {
    float2 s0 = a[0]*b[0], s1 = a[1]*b[1], s2 = a[2]*b[2], s3 = a[3]*b[3];
    #pragma unroll
    for (int j = 4; j < 16; j += 4) {
        s0 += a[j]*b[j]; s1 += a[j+1]*b[j+1]; s2 += a[j+2]*b[j+2]; s3 += a[j+3]*b[j+3];
    }
    float2 s = (s0 + s1) + (s2 + s3);
    return s.x + s.y;
}

// ---------------------------------------------------------------- weight convert+transpose
__global__ __launch_bounds__(256)
void convT_kernel(const float* __restrict__ W, ushort* __restrict__ WT, int K, int N,
                  size_t lStride, int nOff)
{
    __shared__ float t[32][33];
    int k0 = blockIdx.x * 32, n0 = blockIdx.y * 32, L = blockIdx.z;
    const float* Wl = W + (size_t)L * K * N;
    ushort* WTl = WT + (size_t)L * lStride;
    int tx = threadIdx.x & 31, ty = threadIdx.x >> 5;   // 32 x 8
    #pragma unroll
    for (int i = 0; i < 4; ++i)
        t[ty + 8 * i][tx] = Wl[(size_t)(k0 + ty + 8 * i) * N + n0 + tx];
    __syncthreads();
    #pragma unroll
    for (int i = 0; i < 4; ++i)
        WTl[(size_t)(nOff + n0 + ty + 8 * i) * K + k0 + tx] = f2bf(t[tx][ty + 8 * i]);
}

// ---------------------------------------------------------------- fused qkv bias concat: [L][1152]
__global__ __launch_bounds__(384)
void biascat_kernel(const float* __restrict__ bq, const float* __restrict__ bk,
                    const float* __restrict__ bv, float* __restrict__ dst)
{
    int L = blockIdx.x, d = threadIdx.x;
    dst[(size_t)L * DQKV + d]             = bq[(size_t)L * DMODEL + d];
    dst[(size_t)L * DQKV + DMODEL + d]    = bk[(size_t)L * DMODEL + d];
    dst[(size_t)L * DQKV + 2*DMODEL + d]  = bv[(size_t)L * DMODEL + d];
}

// ---------------------------------------------------------------- embedding + LN
__global__ __launch_bounds__(256)
void embed_ln_kernel(const int* __restrict__ ids, const float* __restrict__ we,
                     const float* __restrict__ pe, const float* __restrict__ te,
                     const float* __restrict__ g, const float* __restrict__ bb,
                     float* __restrict__ x, ushort* __restrict__ xb)
{
    int row = blockIdx.x * 4 + (threadIdx.x >> 6);
    int lane = threadIdx.x & 63;
    int l = row & (SEQ - 1);
    int id = ids[row];
    float vals[6];
    float s = 0.f;
    #pragma unroll
    for (int t = 0; t < 6; ++t) {
        int d = lane + 64 * t;
        float v = we[(size_t)id * DMODEL + d] + pe[(size_t)l * DMODEL + d] + te[d];
        vals[t] = v; s += v;
    }
    s = wave_reduce_sum(s);
    float m = s * (1.0f / DMODEL);
    float s2 = 0.f;
    #pragma unroll
    for (int t = 0; t < 6; ++t) { float dd = vals[t] - m; s2 += dd * dd; }
    s2 = wave_reduce_sum(s2);
    float rs = rsqrtf(s2 * (1.0f / DMODEL) + 1e-12f);
    #pragma unroll
    for (int t = 0; t < 6; ++t) {
        int d = lane + 64 * t;
        float val = (vals[t] - m) * rs * g[d] + bb[d];
        x[(size_t)row * DMODEL + d] = val;
        xb[(size_t)row * DMODEL + d] = f2bf(val);
    }
}

// ---------------------------------------------------------------- residual add + LN
__global__ __launch_bounds__(256)
void add_ln_kernel(float* x, ushort* __restrict__ xb, const ushort* __restrict__ r,
                   const float* __restrict__ g, const float* __restrict__ bb)
{
    int row = blockIdx.x * 4 + (threadIdx.x >> 6);
    int lane = threadIdx.x & 63;
    float vals[6];
    float s = 0.f;
    #pragma unroll
    for (int t = 0; t < 6; ++t) {
        int d = lane + 64 * t;
        size_t idx = (size_t)row * DMODEL + d;
        float v = x[idx] + bf2f(r[idx]);
        vals[t] = v; s += v;
    }
    s = wave_reduce_sum(s);
    float m = s * (1.0f / DMODEL);
    float s2 = 0.f;
    #pragma unroll
    for (int t = 0; t < 6; ++t) { float dd = vals[t] - m; s2 += dd * dd; }
    s2 = wave_reduce_sum(s2);
    float rs = rsqrtf(s2 * (1.0f / DMODEL) + 1e-12f);
    #pragma unroll
    for (int t = 0; t < 6; ++t) {
        int d = lane + 64 * t;
        size_t idx = (size_t)row * DMODEL + d;
        float val = (vals[t] - m) * rs * g[d] + bb[d];
        x[idx] = val;
        xb[idx] = f2bf(val);
    }
}

// ---------------------------------------------------------------- bf16 MFMA GEMM, async-staged  [verified R7]
template<typename TC>
__global__ __launch_bounds__(256)
void gemm_mfma(const ushort* __restrict__ A, const ushort* __restrict__ WT,
               const float* __restrict__ bias, TC* __restrict__ C,
               int M, int N, int K, int Astride, int act)
{
    __shared__ __align__(16) ushort As[128 * 64];   // 16 KB
    __shared__ __align__(16) ushort Bs[128 * 64];   // 16 KB
    int tid = threadIdx.x;
    int lane = tid & 63, wv = tid >> 6;
    int waveM = wv >> 1, waveN = wv & 1;
    int lm = lane & 15, quad = lane >> 4;
    int row0 = blockIdx.x * 128, col0 = blockIdx.y * 128;
    int srow = lane >> 3, sseg = lane & 7;          // staging: 8 rows x 8 segs

    f32x4 acc[4][4] = {};

    for (int k0 = 0; k0 < K; k0 += 64) {
        __syncthreads();
        #pragma unroll
        for (int i = 0; i < 4; ++i) {
            int r = wv * 32 + i * 8 + srow;
            int sg = sseg ^ (r & 7);
            async16(A  + (size_t)(row0 + r) * Astride + k0 + sg * 8, &As[(wv * 32 + i * 8) * 64]);
            async16(WT + (size_t)(col0 + r) * K + k0 + sg * 8, &Bs[(wv * 32 + i * 8) * 64]);
        }
        __syncthreads();

        #pragma unroll
        for (int ks = 0; ks < 2; ++ks) {
            int physA = ((ks * 4 + quad) ^ (lm & 7)) * 8;
            bf16x8 af[4], bf[4];
            #pragma unroll
            for (int mt = 0; mt < 4; ++mt)
                af[mt] = *(const bf16x8*)&As[(waveM * 64 + mt * 16 + lm) * 64 + physA];
            #pragma unroll
            for (int nt = 0; nt < 4; ++nt)
                bf[nt] = *(const bf16x8*)&Bs[(waveN * 64 + nt * 16 + lm) * 64 + physA];
            #pragma unroll
            for (int mt = 0; mt < 4; ++mt)
                #pragma unroll
                for (int nt = 0; nt < 4; ++nt)
                    acc[mt][nt] = __builtin_amdgcn_mfma_f32_16x16x32_bf16(af[mt], bf[nt], acc[mt][nt], 0, 0, 0);
        }
    }

    #pragma unroll
    for (int mt = 0; mt < 4; ++mt) {
        #pragma unroll
        for (int nt = 0; nt < 4; ++nt) {
            int col = col0 + waveN * 64 + nt * 16 + lm;
            float bv = bias[col];
            #pragma unroll
            for (int r = 0; r < 4; ++r) {
                int row = row0 + waveM * 64 + mt * 16 + quad * 4 + r;
                float val = acc[mt][nt][r] + bv;
                if (act == 1) val = gelu_tanh(gelu_tanh(val));
                if constexpr (sizeof(TC) == 2)
                    C[(size_t)row * N + col] = f2bf(val);
                else
                    C[(size_t)row * N + col] = val;
            }
        }
    }
}

// ---------------------------------------------------------------- beta  [verified R7]
__global__ __launch_bounds__(256)
void beta_kernel(const ushort* __restrict__ xb, const float* __restrict__ Wb,
                 const float* __restrict__ mask, float* __restrict__ beta)
{
    int row = blockIdx.x * 4 + (threadIdx.x >> 6);
    int lane = threadIdx.x & 63;
    float xr[6];
    #pragma unroll
    for (int t = 0; t < 6; ++t) xr[t] = bf2f(xb[(size_t)row * DMODEL + lane + 64 * t]);
    float mine = 0.f;
    #pragma unroll
    for (int h = 0; h < NH; ++h) {
        float p = 0.f;
        #pragma unroll
        for (int t = 0; t < 6; ++t) p += xr[t] * Wb[(size_t)(lane + 64 * t) * NH + h];
        p = wave_reduce_sum(p);
        if (lane == h) mine = p;
    }
    if (lane < NH) beta[(size_t)row * NH + lane] = sigmoidf(mine) * mask[row];
}

// ---------------------------------------------------------------- chunk-parallel scan v10
// R8 data: v6..v9 wall == VALU-work / ~25% issue eff -> the binding constraint
// is PARALLELISM (384 waves on 1024 SIMDs), not the inner loop. v10 makes it
// 3-phase over PSEG=4 segments (recurrence S_t = M_t S_{t-1} + u_t is affine,
// M_t = g I - beta k k^T):
//  A: per (bh,seg,state): local S_end (from 0) + transition A = prod(M).
//     6144 half-wave tasks = 3072 waves = 12 waves/CU.
//  B: per (bh,state): serial over 4 segs: Sstart[seg]=S; S = A*S + Send
//     (in-place over the Send buffer; vmcnt(0) between read and overwrite).
//  C: per (bh,seg): v7 scan, 128 steps, S init from Sstart; writes o.
//     3072 half-wave tasks = 1536 waves = 6 waves/CU.
// Exact f32 algebra; buffers (f32): Astore == dead xb (25.17MB, exact),
// Send/Sstart == dead ab (25.17MB, exact).
// Layout: Astore/Send[((bh*4+seg)*2+state)*1024 + n*32 + k]; entry = col n,
// row k of the 32x32 matrix (lane n owns column n contiguously).

__global__ __launch_bounds__(64)
void scanA_kernel(const ushort* __restrict__ qkv, const float* __restrict__ beta,
                  const float* __restrict__ mask,
                  const float* __restrict__ dfast, const float* __restrict__ dslow,
                  float* __restrict__ Astore, float* __restrict__ Send)
{
    __shared__ __align__(16) float ks[SCAN_T][SPAD];
    __shared__ __align__(16) float vs[SCAN_T][SPAD];
    __shared__ float bs[SCAN_T];

    int lane = threadIdx.x;
    int half = lane >> 5, n = lane & 31;
    int blk = blockIdx.x;            // 3072: (bh, seg); halves = the 2 states
    int state = half;
    int seg = blk & 3;
    int bh  = blk >> 2;
    int b = bh / NH, h = bh % NH;
    float g = sigmoidf(state ? dslow[h] : dfast[h]);
    float2 gv = make_float2(g, g);

    float2 S[16], A[16];
    #pragma unroll
    for (int j = 0; j < 16; ++j) {
        S[j] = make_float2(0.f, 0.f);
        A[j].x = (2 * j     == n) ? 1.f : 0.f;   // A = I (column n)
        A[j].y = (2 * j + 1 == n) ? 1.f : 0.f;
    }

    // prefetch regs (half 0 stages the shared tile: same (bh,seg) for both halves)
    uint4 pk4[4], pv4[4];
    float pb = 0.f, pmk = 0.f;
    if (half == 0) {
        size_t ra = (size_t)(b * SEQ + seg * TSEG + n) * DQKV + h * DHEAD;
        #pragma unroll
        for (int s = 0; s < 4; ++s) {
            pk4[s] = *(const uint4*)(qkv + ra + DMODEL + s * 8);
            pv4[s] = *(const uint4*)(qkv + ra + 2 * DMODEL + s * 8);
        }
        pb  = beta[(size_t)(b * SEQ + seg * TSEG + n) * NH + h];
        pmk = mask[b * SEQ + seg * TSEG + n];
    }

    for (int tt = 0; tt < TSEG; tt += SCAN_T) {
        __syncthreads();
        if (half == 0) {
            ushort tk[32], tv[32];
            #pragma unroll
            for (int s = 0; s < 4; ++s) {
                *(uint4*)(tk + s * 8) = pk4[s];
                *(uint4*)(tv + s * 8) = pv4[s];
            }
            float kv[32];
            float sk = 0.f;
            #pragma unroll
            for (int j = 0; j < 32; ++j) { kv[j] = bf2f(tk[j]); sk += kv[j] * kv[j]; }
            float rk = pmk / (sqrtf(sk) + 1e-6f);
            #pragma unroll
            for (int s = 0; s < 8; ++s) {
                float4 fk, fv;
                fk.x = kv[s*4+0]*rk; fk.y = kv[s*4+1]*rk; fk.z = kv[s*4+2]*rk; fk.w = kv[s*4+3]*rk;
                fv.x = bf2f(tv[s*4+0]); fv.y = bf2f(tv[s*4+1]); fv.z = bf2f(tv[s*4+2]); fv.w = bf2f(tv[s*4+3]);
                *(float4*)&ks[n][s * 4] = fk;
                *(float4*)&vs[n][s * 4] = fv;
            }
            bs[n] = pb;
        }
        __syncthreads();
        if (half == 0 && tt + SCAN_T < TSEG) {
            size_t ra = (size_t)(b * SEQ + seg * TSEG + tt + SCAN_T + n) * DQKV + h * DHEAD;
            #pragma unroll
            for (int s = 0; s < 4; ++s) {
                pk4[s] = *(const uint4*)(qkv + ra + DMODEL + s * 8);
                pv4[s] = *(const uint4*)(qkv + ra + 2 * DMODEL + s * 8);
            }
            pb  = beta[(size_t)(b * SEQ + seg * TSEG + tt + SCAN_T + n) * NH + h];
            pmk = mask[b * SEQ + seg * TSEG + tt + SCAN_T + n];
        }

        #pragma unroll 4
        for (int t = 0; t < SCAN_T; ++t) {
            float2 kt[16];
            #pragma unroll
            for (int s = 0; s < 8; ++s)
                *(float4*)&kt[s * 2] = *(const float4*)&ks[t][s * 4];
            float vt = vs[t][n], bt = bs[t];

            float p  = dot16(kt, S);
            float ap = dot16(kt, A);
            float c  = bt * (vt - p);
            float ca = bt * ap;
            float2 cv = make_float2(c, c), cav = make_float2(ca, ca);
            #pragma unroll
            for (int j = 0; j < 16; ++j) {
                S[j] = gv * S[j] + kt[j] * cv;
                A[j] = gv * A[j] - kt[j] * cav;
            }
        }
    }

    size_t base = (((size_t)bh * PSEG + seg) * 2 + state) * 1024 + (size_t)n * 32;
    #pragma unroll
    for (int s = 0; s < 8; ++s) {
        *(float4*)(Send   + base + s * 4) = *(float4*)&S[s * 2];
        *(float4*)(Astore + base + s * 4) = *(float4*)&A[s * 2];
    }
}

__global__ __launch_bounds__(64)
void combine_kernel(const float* __restrict__ Astore, float* __restrict__ Send)
{
    __shared__ __align__(16) float As[2][32][SPAD];
    int lane = threadIdx.x;
    int half = lane >> 5, n = lane & 31;
    int bh = blockIdx.x;     // 768; halves = 2 states
    int state = half;

    float Sc[32];
    #pragma unroll
    for (int k = 0; k < 32; ++k) Sc[k] = 0.f;

    for (int seg = 0; seg < PSEG; ++seg) {
        size_t base = (((size_t)bh * PSEG + seg) * 2 + state) * 1024 + (size_t)n * 32;
        #pragma unroll
        for (int s = 0; s < 8; ++s)
            *(float4*)&As[state][n][s * 4] = *(const float4*)(Astore + base + s * 4);
        __syncthreads();

        float tmp[32];
        #pragma unroll
        for (int s = 0; s < 8; ++s)
            *(float4*)&tmp[s * 4] = *(const float4*)(Send + base + s * 4);
        asm volatile("s_waitcnt vmcnt(0)" ::: "memory");   // tmp loaded before overwrite
        #pragma unroll
        for (int s = 0; s < 8; ++s)
            *(float4*)(Send + base + s * 4) = *(float4*)&Sc[s * 4];   // Sstart[seg]

        float acc[32];
        #pragma unroll
        for (int k = 0; k < 32; ++k) acc[k] = tmp[k];
        #pragma unroll
        for (int j = 0; j < 32; ++j) {       // newS[k] = sum_j A[k][j]*Sc[j] + tmp[k]
            float sj = Sc[j];
            #pragma unroll
            for (int s = 0; s < 8; ++s) {
                float4 ar = *(const float4*)&As[state][j][s * 4];   // A[s*4..][j]
                acc[s*4+0] += ar.x * sj;
                acc[s*4+1] += ar.y * sj;
                acc[s*4+2] += ar.z * sj;
                acc[s*4+3] += ar.w * sj;
            }
        }
        #pragma unroll
        for (int k = 0; k < 32; ++k) Sc[k] = acc[k];
        __syncthreads();
    }
}

__global__ __launch_bounds__(64)
void scanC_kernel(const ushort* __restrict__ qkv, const float* __restrict__ beta,
                  const float* __restrict__ mask,
                  const float* __restrict__ dfast, const float* __restrict__ dslow,
                  const float* __restrict__ Sstart, ushort* __restrict__ o)
{
    __shared__ __align__(16) float qs[2][SCAN_T][SPAD];
    __shared__ __align__(16) float ks[2][SCAN_T][SPAD];
    __shared__ __align__(16) float vs[2][SCAN_T][SPAD];
    __shared__ float bs[2][SCAN_T];

    int lane = threadIdx.x;
    int half = lane >> 5, n = lane & 31;
    int task = blockIdx.x * 2 + half;   // 1536 blocks; halves share bh, differ in seg
    int seg = task & 3, bh = task >> 2;
    int myb = bh / NH, myh = bh % NH;
    int rowbase = myb * SEQ + seg * TSEG;

    float gf = sigmoidf(dfast[myh]);
    float gsl = sigmoidf(dslow[myh]);
    float2 gf2 = make_float2(gf, gf), gs2 = make_float2(gsl, gsl);

    float2 Sf[16], Ss[16];
    {
        size_t sb = (((size_t)bh * PSEG + seg) * 2 + 0) * 1024 + (size_t)n * 32;
        #pragma unroll
        for (int s = 0; s < 8; ++s) {
            *(float4*)&Sf[s * 2] = *(const float4*)(Sstart + sb + s * 4);
            *(float4*)&Ss[s * 2] = *(const float4*)(Sstart + sb + 1024 + s * 4);
        }
    }

    uint4 pq[4], pk[4], pv[4];
    float pb, pmk;
    {
        size_t ra = (size_t)(rowbase + n) * DQKV + myh * DHEAD;
        #pragma unroll
        for (int s = 0; s < 4; ++s) {
            pq[s] = *(const uint4*)(qkv + ra + s * 8);
            pk[s] = *(const uint4*)(qkv + ra + DMODEL + s * 8);
            pv[s] = *(const uint4*)(qkv + ra + 2 * DMODEL + s * 8);
        }
        pb  = beta[(size_t)(rowbase + n) * NH + myh];
        pmk = mask[rowbase + n];
    }

    for (int tt = 0; tt < TSEG; tt += SCAN_T) {
        __syncthreads();
        {
            ushort tq[32], tk[32], tv[32];
            #pragma unroll
            for (int s = 0; s < 4; ++s) {
                *(uint4*)(tq + s * 8) = pq[s];
                *(uint4*)(tk + s * 8) = pk[s];
                *(uint4*)(tv + s * 8) = pv[s];
            }
            float qv[32], kv[32];
            float sq = 0.f, sk = 0.f;
            #pragma unroll
            for (int j = 0; j < 32; ++j) {
                qv[j] = bf2f(tq[j]); sq += qv[j] * qv[j];
                kv[j] = bf2f(tk[j]); sk += kv[j] * kv[j];
            }
            float rq = 1.0f / (sqrtf(sq) + 1e-6f);
            float rk = pmk / (sqrtf(sk) + 1e-6f);
            #pragma unroll
            for (int s = 0; s < 8; ++s) {
                float4 fq, fk, fv;
                fq.x = qv[s*4+0]*rq; fq.y = qv[s*4+1]*rq; fq.z = qv[s*4+2]*rq; fq.w = qv[s*4+3]*rq;
                fk.x = kv[s*4+0]*rk; fk.y = kv[s*4+1]*rk; fk.z = kv[s*4+2]*rk; fk.w = kv[s*4+3]*rk;
                fv.x = bf2f(tv[s*4+0]); fv.y = bf2f(tv[s*4+1]); fv.z = bf2f(tv[s*4+2]); fv.w = bf2f(tv[s*4+3]);
                *(float4*)&qs[half][n][s * 4] = fq;
                *(float4*)&ks[half][n][s * 4] = fk;
                *(float4*)&vs[half][n][s * 4] = fv;
            }
            bs[half][n] = pb;
        }
        __syncthreads();

        if (tt + SCAN_T < TSEG) {   // prefetch stays INSIDE own segment (hazard: other segs' o-writes)
            size_t ra = (size_t)(rowbase + tt + SCAN_T + n) * DQKV + myh * DHEAD;
            #pragma unroll
            for (int s = 0; s < 4; ++s) {
                pq[s] = *(const uint4*)(qkv + ra + s * 8);
                pk[s] = *(const uint4*)(qkv + ra + DMODEL + s * 8);
                pv[s] = *(const uint4*)(qkv + ra + 2 * DMODEL + s * 8);
            }
            pb  = beta[(size_t)(rowbase + tt + SCAN_T + n) * NH + myh];
            pmk = mask[rowbase + tt + SCAN_T + n];
        }

        #pragma unroll 4
        for (int t = 0; t < SCAN_T; ++t) {
            float2 kt[16], qt[16];
            #pragma unroll
            for (int s = 0; s < 8; ++s) {
                *(float4*)&kt[s * 2] = *(const float4*)&ks[half][t][s * 4];
                *(float4*)&qt[s * 2] = *(const float4*)&qs[half][t][s * 4];
            }
            float vt = vs[half][t][n], bt = bs[half][t];

            float2 pf0 = kt[0] * Sf[0], pf1 = kt[1] * Sf[1], pf2 = kt[2] * Sf[2], pf3 = kt[3] * Sf[3];
            float2 ps0 = kt[0] * Ss[0], ps1 = kt[1] * Ss[1], ps2 = kt[2] * Ss[2], ps3 = kt[3] * Ss[3];
            #pragma unroll
            for (int j = 4; j < 16; j += 4) {
                pf0 += kt[j] * Sf[j];     pf1 += kt[j + 1] * Sf[j + 1];
                pf2 += kt[j + 2] * Sf[j + 2]; pf3 += kt[j + 3] * Sf[j + 3];
                ps0 += kt[j] * Ss[j];     ps1 += kt[j + 1] * Ss[j + 1];
                ps2 += kt[j + 2] * Ss[j + 2]; ps3 += kt[j + 3] * Ss[j + 3];
            }
            float2 pfv = (pf0 + pf1) + (pf2 + pf3);
            float2 psv = (ps0 + ps1) + (ps2 + ps3);
            float pft = pfv.x + pfv.y, pst = psv.x + psv.y;

            float cf = bt * (vt - pft), cs = bt * (vt - pst);
            float2 cf2 = make_float2(cf, cf), cs2 = make_float2(cs, cs);

            float2 o0 = make_float2(0.f, 0.f), o1 = o0, o2 = o0, o3 = o0;
            #pragma unroll
            for (int j = 0; j < 16; j += 4) {
                Sf[j] = gf2 * Sf[j] + kt[j] * cf2;         Ss[j] = gs2 * Ss[j] + kt[j] * cs2;
                Sf[j+1] = gf2 * Sf[j+1] + kt[j+1] * cf2;   Ss[j+1] = gs2 * Ss[j+1] + kt[j+1] * cs2;
                Sf[j+2] = gf2 * Sf[j+2] + kt[j+2] * cf2;   Ss[j+2] = gs2 * Ss[j+2] + kt[j+2] * cs2;
                Sf[j+3] = gf2 * Sf[j+3] + kt[j+3] * cf2;   Ss[j+3] = gs2 * Ss[j+3] + kt[j+3] * cs2;
                o0 += qt[j] * (Sf[j] + Ss[j]);
                o1 += qt[j+1] * (Sf[j+1] + Ss[j+1]);
                o2 += qt[j+2] * (Sf[j+2] + Ss[j+2]);
                o3 += qt[j+3] * (Sf[j+3] + Ss[j+3]);
            }
            float2 ov = (o0 + o1) + (o2 + o3);
            float ott = ov.x + ov.y;
            o[((size_t)(rowbase + tt + t)) * DQKV + myh * DHEAD + n] = f2bf(0.5f * ott);
        }
    }
}

// ---------------------------------------------------------------- masked mean-pool + l2 normalize
__global__ __launch_bounds__(384)
void pool_kernel(const float* __restrict__ x, const float* __restrict__ mask,
                 float* __restrict__ out)
{
    int b = blockIdx.x;
    int d = threadIdx.x;
    float acc = 0.f, msum = 0.f;
    for (int l = 0; l < SEQ; ++l) {
        float mk = mask[b * SEQ + l];
        acc += x[((size_t)b * SEQ + l) * DMODEL + d] * mk;
        msum += mk;
    }
    float emb = acc / fmaxf(msum, 1e-9f);
    __shared__ float red[6];
    float ss = wave_reduce_sum(emb * emb);
    int wvi = d >> 6, ln = d & 63;
    if (ln == 0) red[wvi] = ss;
    __syncthreads();
    float tot = 0.f;
    #pragma unroll
    for (int i = 0; i < 6; ++i) tot += red[i];
    float nrm = fmaxf(sqrtf(tot), 1e-12f);
    out[(size_t)b * DMODEL + d] = emb / nrm;
}

// ---------------------------------------------------------------- launch

extern "C" void kernel_launch(void* const* d_in, const int* in_sizes, int n_in,
                              void* d_out, int out_size, void* d_ws, size_t ws_size,
                              hipStream_t stream)
{
    const int*   ids   = (const int*)d_in[0];
    const float* mask  = (const float*)d_in[1];
    const float* we    = (const float*)d_in[2];
    const float* pe    = (const float*)d_in[3];
    const float* te    = (const float*)d_in[4];
    const float* elg   = (const float*)d_in[5];
    const float* elb   = (const float*)d_in[6];
    const float* Wq    = (const float*)d_in[7];
    const float* bq    = (const float*)d_in[8];
    const float* Wk    = (const float*)d_in[9];
    const float* bk    = (const float*)d_in[10];
    const float* Wv    = (const float*)d_in[11];
    const float* bv    = (const float*)d_in[12];
    const float* Wb    = (const float*)d_in[13];
    const float* dfast = (const float*)d_in[14];
    const float* dslow = (const float*)d_in[15];
    const float* Wo    = (const float*)d_in[16];
    const float* bo    = (const float*)d_in[17];
    const float* l1g   = (const float*)d_in[18];
    const float* l1b   = (const float*)d_in[19];
    const float* W1    = (const float*)d_in[20];
    const float* b1    = (const float*)d_in[21];
    const float* W2    = (const float*)d_in[22];
    const float* b2    = (const float*)d_in[23];
    const float* l2g   = (const float*)d_in[24];
    const float* l2b   = (const float*)d_in[25];
    float* out = (float*)d_out;

    // ---- workspace: 199.0 MB total (proven ceiling 202.9 MB, R4) ----
    const size_t RD = (size_t)NROWS * DMODEL;    // 12,582,912 elements
    float* x      = (float*)d_ws;                      // 50.33 MB
    float* betab  = x + RD;                            //  1.57 MB
    ushort* xb    = (ushort*)(betab + (size_t)NROWS * NH);   // 25.17 MB
    ushort* qkvb  = xb + RD;                           // 75.50 MB  [row][1152]
    ushort* ab    = qkvb + (size_t)NROWS * DQKV;       // 25.17 MB (attn out / FFN W2-out)
    ushort* WqkvT = ab + RD;                           //  5.31 MB [L][1152][384]
    ushort* WoT   = WqkvT + (size_t)NLAYER * DQKV * DMODEL;  // 1.77 MB
    ushort* W1T   = WoT + (size_t)NLAYER * DMODEL * DMODEL;  // 7.08 MB [L][1536][384]
    ushort* W2T   = W1T + (size_t)NLAYER * DMODEL * DFFN;    // 7.08 MB [L][384][1536]
    float* biasqkv = (float*)(W2T + (size_t)NLAYER * DFFN * DMODEL); // 27 KB

    // scan-phase scratch (dead windows): A in xb (exactly 25,165,824 B),
    // Send/Sstart in ab (exactly 25,165,824 B), both as f32.
    float* Asto = (float*)xb;
    float* Sen  = (float*)ab;

    dim3 blk256(256);
    dim3 rowsGrid(NROWS / 4);
    dim3 gemmGrid_QKV(NROWS / 128, DQKV / 128);      // (256, 9)
    dim3 gemmGrid_D(NROWS / 128, DMODEL / 128);      // (256, 3)
    dim3 gemmGrid_C1(FFN_CHUNK / 128, DFFN / 128);   // (128, 12)
    dim3 gemmGrid_C2(FFN_CHUNK / 128, DMODEL / 128); // (128, 3)
    dim3 chunkRows(FFN_CHUNK / 4);

    const size_t lsQKV = (size_t)DQKV * DMODEL;
    convT_kernel<<<dim3(12, 12, NLAYER), blk256, 0, stream>>>(Wq, WqkvT, DMODEL, DMODEL, lsQKV, 0);
    convT_kernel<<<dim3(12, 12, NLAYER), blk256, 0, stream>>>(Wk, WqkvT, DMODEL, DMODEL, lsQKV, DMODEL);
    convT_kernel<<<dim3(12, 12, NLAYER), blk256, 0, stream>>>(Wv, WqkvT, DMODEL, DMODEL, lsQKV, 2*DMODEL);
    convT_kernel<<<dim3(12, 12, NLAYER), blk256, 0, stream>>>(Wo, WoT, DMODEL, DMODEL, (size_t)DMODEL*DMODEL, 0);
    convT_kernel<<<dim3(12, 48, NLAYER), blk256, 0, stream>>>(W1, W1T, DMODEL, DFFN, (size_t)DMODEL*DFFN, 0);
    convT_kernel<<<dim3(48, 12, NLAYER), blk256, 0, stream>>>(W2, W2T, DFFN, DMODEL, (size_t)DFFN*DMODEL, 0);
    biascat_kernel<<<dim3(NLAYER), dim3(384), 0, stream>>>(bq, bk, bv, biasqkv);

    embed_ln_kernel<<<rowsGrid, blk256, 0, stream>>>(ids, we, pe, te, elg, elb, x, xb);

    for (int i = 0; i < NLAYER; ++i) {
        const ushort* WqkvT_i = WqkvT + (size_t)i * lsQKV;
        const ushort* WoT_i   = WoT + (size_t)i * DMODEL * DMODEL;
        const float*  Wb_i    = Wb  + (size_t)i * DMODEL * NH;
        const ushort* W1T_i   = W1T + (size_t)i * DMODEL * DFFN;
        const ushort* W2T_i   = W2T + (size_t)i * DFFN * DMODEL;

        gemm_mfma<ushort><<<gemmGrid_QKV, blk256, 0, stream>>>(xb, WqkvT_i, biasqkv + (size_t)i * DQKV,
                                                               qkvb, NROWS, DQKV, DMODEL, DMODEL, 0);
        beta_kernel<<<rowsGrid, blk256, 0, stream>>>(xb, Wb_i, mask, betab);
        // chunk-parallel scan: A (parallel) -> B (combine) -> C (outputs into q-section)
        scanA_kernel<<<dim3(BATCH * NH * PSEG), dim3(64), 0, stream>>>(qkvb, betab, mask,
                                                                       dfast + i * NH, dslow + i * NH,
                                                                       Asto, Sen);
        combine_kernel<<<dim3(BATCH * NH), dim3(64), 0, stream>>>(Asto, Sen);
        scanC_kernel<<<dim3(BATCH * NH * PSEG / 2), dim3(64), 0, stream>>>(qkvb, betab, mask,
                                                                           dfast + i * NH, dslow + i * NH,
                                                                           Sen, qkvb);
        // Wo GEMM reads strided o (Astride = DQKV)
        gemm_mfma<ushort><<<gemmGrid_D, blk256, 0, stream>>>(qkvb, WoT_i, bo + i * DMODEL, ab,
                                                             NROWS, DMODEL, DMODEL, DQKV, 0);
        add_ln_kernel<<<rowsGrid, blk256, 0, stream>>>(x, xb, ab, l1g + i * DMODEL, l1b + i * DMODEL);

        // FFN in 2 chunks (h -> qkvb front, dead; W2-out -> ab, dead)
        for (int c = 0; c < NROWS / FFN_CHUNK; ++c) {
            const ushort* xc = xb + (size_t)c * FFN_CHUNK * DMODEL;
            ushort* hbuf  = qkvb;
            ushort* w2out = ab + (size_t)c * FFN_CHUNK * DMODEL;
            gemm_mfma<ushort><<<gemmGrid_C1, blk256, 0, stream>>>(xc, W1T_i, b1 + i * DFFN, hbuf,
                                                                  FFN_CHUNK, DFFN, DMODEL, DMODEL, 1);
            gemm_mfma<ushort><<<gemmGrid_C2, blk256, 0, stream>>>(hbuf, W2T_i, b2 + i * DMODEL, w2out,
                                                                  FFN_CHUNK, DMODEL, DFFN, DFFN, 0);
            add_ln_kernel<<<chunkRows, blk256, 0, stream>>>(x + (size_t)c * FFN_CHUNK * DMODEL,
                                                            xb + (size_t)c * FFN_CHUNK * DMODEL, w2out,
                                                            l2g + i * DMODEL, l2b + i * DMODEL);
        }
    }

    pool_kernel<<<dim3(BATCH), dim3(384), 0, stream>>>(x, mask, out);
}

// Round 10
// 3341.032 us; speedup vs baseline: 1.2128x; 1.2128x over previous
//
#include <hip/hip_runtime.h>
#include <cstdint>
#include <cstddef>
#include <cmath>

#define NLAYER 6
#define NH 12
#define DMODEL 384
#define DHEAD 32
#define DFFN 1536
#define BATCH 64
#define SEQ 512
#define NROWS (BATCH*SEQ)   // 32768
#define DQKV 1152           // fused q|k|v row length
#define FFN_CHUNK 16384     // 2 chunks; h buffer reused (sequential chunks)

typedef unsigned short ushort;
typedef __attribute__((ext_vector_type(8))) short bf16x8;   // 8 bf16 = 4 VGPRs
typedef __attribute__((ext_vector_type(4))) float f32x4;

// ---------------------------------------------------------------- utilities

__device__ inline float bf2f(ushort u) {
    union { unsigned int i; float f; } c; c.i = ((unsigned int)u) << 16; return c.f;
}
__device__ inline ushort f2bf(float f) {
    union { float f; unsigned int i; } c; c.f = f;
    unsigned int i = c.i;
    unsigned int lsb = (i >> 16) & 1u;
    i += 0x7fffu + lsb;          // round-to-nearest-even
    return (ushort)(i >> 16);
}

__device__ inline float wave_reduce_sum(float v) {
    #pragma unroll
    for (int m = 32; m >= 1; m >>= 1) v += __shfl_xor(v, m, 64);
    return v;
}

__device__ inline float sigmoidf(float x) { return 1.0f / (1.0f + expf(-x)); }

__device__ inline float gelu_tanh(float x) {
    const float c = 0.7978845608028654f; // sqrt(2/pi)
    float t = tanhf(c * (x + 0.044715f * x * x * x));
    return 0.5f * x * (1.0f + t);
}

// async global->LDS, 16 bytes per lane; lds base must be wave-uniform
__device__ inline void async16(const ushort* g, ushort* l) {
    __builtin_amdgcn_global_load_lds(
        (const __attribute__((address_space(1))) unsigned int*)g,
        (__attribute__((address_space(3))) unsigned int*)l,
        16, 0, 0);
}

// ---------------------------------------------------------------- weight convert+transpose
// W fp32 [L][K][N] -> WT bf16 rows of K elements; layer stride lStride,
// dest row offset nOff (fused QKV packing).
__global__ __launch_bounds__(256)
void convT_kernel(const float* __restrict__ W, ushort* __restrict__ WT, int K, int N,
                  size_t lStride, int nOff)
{
    __shared__ float t[32][33];
    int k0 = blockIdx.x * 32, n0 = blockIdx.y * 32, L = blockIdx.z;
    const float* Wl = W + (size_t)L * K * N;
    ushort* WTl = WT + (size_t)L * lStride;
    int tx = threadIdx.x & 31, ty = threadIdx.x >> 5;   // 32 x 8
    #pragma unroll
    for (int i = 0; i < 4; ++i)
        t[ty + 8 * i][tx] = Wl[(size_t)(k0 + ty + 8 * i) * N + n0 + tx];
    __syncthreads();
    #pragma unroll
    for (int i = 0; i < 4; ++i)
        WTl[(size_t)(nOff + n0 + ty + 8 * i) * K + k0 + tx] = f2bf(t[tx][ty + 8 * i]);
}

// ---------------------------------------------------------------- fused qkv bias concat: [L][1152]
__global__ __launch_bounds__(384)
void biascat_kernel(const float* __restrict__ bq, const float* __restrict__ bk,
                    const float* __restrict__ bv, float* __restrict__ dst)
{
    int L = blockIdx.x, d = threadIdx.x;
    dst[(size_t)L * DQKV + d]             = bq[(size_t)L * DMODEL + d];
    dst[(size_t)L * DQKV + DMODEL + d]    = bk[(size_t)L * DMODEL + d];
    dst[(size_t)L * DQKV + 2*DMODEL + d]  = bv[(size_t)L * DMODEL + d];
}

// ---------------------------------------------------------------- embedding + LN (writes fp32 x and bf16 xb)
__global__ __launch_bounds__(256)
void embed_ln_kernel(const int* __restrict__ ids, const float* __restrict__ we,
                     const float* __restrict__ pe, const float* __restrict__ te,
                     const float* __restrict__ g, const float* __restrict__ bb,
                     float* __restrict__ x, ushort* __restrict__ xb)
{
    int row = blockIdx.x * 4 + (threadIdx.x >> 6);
    int lane = threadIdx.x & 63;
    int l = row & (SEQ - 1);
    int id = ids[row];
    float vals[6];
    float s = 0.f;
    #pragma unroll
    for (int t = 0; t < 6; ++t) {
        int d = lane + 64 * t;
        float v = we[(size_t)id * DMODEL + d] + pe[(size_t)l * DMODEL + d] + te[d];
        vals[t] = v; s += v;
    }
    s = wave_reduce_sum(s);
    float m = s * (1.0f / DMODEL);
    float s2 = 0.f;
    #pragma unroll
    for (int t = 0; t < 6; ++t) { float dd = vals[t] - m; s2 += dd * dd; }
    s2 = wave_reduce_sum(s2);
    float rs = rsqrtf(s2 * (1.0f / DMODEL) + 1e-12f);
    #pragma unroll
    for (int t = 0; t < 6; ++t) {
        int d = lane + 64 * t;
        float val = (vals[t] - m) * rs * g[d] + bb[d];
        x[(size_t)row * DMODEL + d] = val;
        xb[(size_t)row * DMODEL + d] = f2bf(val);
    }
}

// ---------------------------------------------------------------- residual add + LN (fp32 x in-place; bf16 branch; writes xb)
__global__ __launch_bounds__(256)
void add_ln_kernel(float* x, ushort* __restrict__ xb, const ushort* __restrict__ r,
                   const float* __restrict__ g, const float* __restrict__ bb)
{
    int row = blockIdx.x * 4 + (threadIdx.x >> 6);
    int lane = threadIdx.x & 63;
    float vals[6];
    float s = 0.f;
    #pragma unroll
    for (int t = 0; t < 6; ++t) {
        int d = lane + 64 * t;
        size_t idx = (size_t)row * DMODEL + d;
        float v = x[idx] + bf2f(r[idx]);
        vals[t] = v; s += v;
    }
    s = wave_reduce_sum(s);
    float m = s * (1.0f / DMODEL);
    float s2 = 0.f;
    #pragma unroll
    for (int t = 0; t < 6; ++t) { float dd = vals[t] - m; s2 += dd * dd; }
    s2 = wave_reduce_sum(s2);
    float rs = rsqrtf(s2 * (1.0f / DMODEL) + 1e-12f);
    #pragma unroll
    for (int t = 0; t < 6; ++t) {
        int d = lane + 64 * t;
        size_t idx = (size_t)row * DMODEL + d;
        float val = (vals[t] - m) * rs * g[d] + bb[d];
        x[idx] = val;
        xb[idx] = f2bf(val);
    }
}

// ---------------------------------------------------------------- bf16 MFMA GEMM, async-staged  [verified R7]
// A row stride Astride (elements) may differ from K (strided o-section reads).
template<typename TC>
__global__ __launch_bounds__(256)
void gemm_mfma(const ushort* __restrict__ A, const ushort* __restrict__ WT,
               const float* __restrict__ bias, TC* __restrict__ C,
               int M, int N, int K, int Astride, int act)
{
    __shared__ __align__(16) ushort As[128 * 64];   // 16 KB
    __shared__ __align__(16) ushort Bs[128 * 64];   // 16 KB
    int tid = threadIdx.x;
    int lane = tid & 63, wv = tid >> 6;
    int waveM = wv >> 1, waveN = wv & 1;
    int lm = lane & 15, quad = lane >> 4;
    int row0 = blockIdx.x * 128, col0 = blockIdx.y * 128;
    int srow = lane >> 3, sseg = lane & 7;          // staging: 8 rows x 8 segs

    f32x4 acc[4][4] = {};

    for (int k0 = 0; k0 < K; k0 += 64) {
        __syncthreads();
        #pragma unroll
        for (int i = 0; i < 4; ++i) {
            int r = wv * 32 + i * 8 + srow;
            int sg = sseg ^ (r & 7);
            async16(A  + (size_t)(row0 + r) * Astride + k0 + sg * 8, &As[(wv * 32 + i * 8) * 64]);
            async16(WT + (size_t)(col0 + r) * K + k0 + sg * 8, &Bs[(wv * 32 + i * 8) * 64]);
        }
        __syncthreads();

        #pragma unroll
        for (int ks = 0; ks < 2; ++ks) {
            int physA = ((ks * 4 + quad) ^ (lm & 7)) * 8;
            bf16x8 af[4], bf[4];
            #pragma unroll
            for (int mt = 0; mt < 4; ++mt)
                af[mt] = *(const bf16x8*)&As[(waveM * 64 + mt * 16 + lm) * 64 + physA];
            #pragma unroll
            for (int nt = 0; nt < 4; ++nt)
                bf[nt] = *(const bf16x8*)&Bs[(waveN * 64 + nt * 16 + lm) * 64 + physA];
            #pragma unroll
            for (int mt = 0; mt < 4; ++mt)
                #pragma unroll
                for (int nt = 0; nt < 4; ++nt)
                    acc[mt][nt] = __builtin_amdgcn_mfma_f32_16x16x32_bf16(af[mt], bf[nt], acc[mt][nt], 0, 0, 0);
        }
    }

    #pragma unroll
    for (int mt = 0; mt < 4; ++mt) {
        #pragma unroll
        for (int nt = 0; nt < 4; ++nt) {
            int col = col0 + waveN * 64 + nt * 16 + lm;
            float bv = bias[col];
            #pragma unroll
            for (int r = 0; r < 4; ++r) {
                int row = row0 + waveM * 64 + mt * 16 + quad * 4 + r;
                float val = acc[mt][nt][r] + bv;
                if (act == 1) val = gelu_tanh(gelu_tanh(val));
                if constexpr (sizeof(TC) == 2)
                    C[(size_t)row * N + col] = f2bf(val);
                else
                    C[(size_t)row * N + col] = val;
            }
        }
    }
}

// ---------------------------------------------------------------- beta: wave per row, coalesced bf16 x  [verified R7]
__global__ __launch_bounds__(256)
void beta_kernel(const ushort* __restrict__ xb, const float* __restrict__ Wb,
                 const float* __restrict__ mask, float* __restrict__ beta)
{
    int row = blockIdx.x * 4 + (threadIdx.x >> 6);
    int lane = threadIdx.x & 63;
    float xr[6];
    #pragma unroll
    for (int t = 0; t < 6; ++t) xr[t] = bf2f(xb[(size_t)row * DMODEL + lane + 64 * t]);
    float mine = 0.f;
    #pragma unroll
    for (int h = 0; h < NH; ++h) {
        float p = 0.f;
        #pragma unroll
        for (int t = 0; t < 6; ++t) p += xr[t] * Wb[(size_t)(lane + 64 * t) * NH + h];
        p = wave_reduce_sum(p);
        if (lane == h) mine = p;
    }
    if (lane < NH) beta[(size_t)row * NH + lane] = sigmoidf(mine) * mask[row];
}

// ---------------------------------------------------------------- delta-rule scan v7 [BEST MEASURED: 216 us, R4]
// Wave serves 2 (b,h): half = lane>>5 picks bh, n = lane&31 = state column.
// Lane owns the FULL 32-deep k state for column n (float2-packed). All math
// in-lane: no shfl/bpermute in the loop. Staging: lane stages full row t0+n
// of its bh with fused q/k l2norm + k*mask. Next tile prefetched to regs
// (vmcnt only). Per-step LDS reads: k/q rows are half-wave broadcasts;
// vs[t][n] stride-1 -- conflict-free.
// o writes into the q-section of qkv (rows < t0+32; prefetch reads >= t0+32).
// Session ledger: v6 (k-split + shfl) 208, v7 216, v8 (src pipeline) 230,
// v9 (2-step fusion) 260, v10 (chunk-parallel 3-phase) ~324/layer -- every
// restructuring of the VALU scan lands ~1000 cyc/step; v7 kept as optimum.
#define SCAN_T 32
#define SPAD 36
__global__ __launch_bounds__(64)
void scan_kernel(const ushort* __restrict__ qkv, const float* __restrict__ beta,
                 const float* __restrict__ mask,
                 const float* __restrict__ dfast, const float* __restrict__ dslow,
                 ushort* __restrict__ o)
{
    __shared__ __align__(16) float qs[2][SCAN_T][SPAD];
    __shared__ __align__(16) float ks[2][SCAN_T][SPAD];
    __shared__ __align__(16) float vs[2][SCAN_T][SPAD];
    __shared__ float bs[2][SCAN_T];

    int gw = blockIdx.x;
    int lane = threadIdx.x;
    int half = lane >> 5, n = lane & 31;
    int bh = gw * 2 + half;
    int myb = bh / NH, myh = bh % NH;

    float gf = sigmoidf(dfast[myh]);
    float gsl = sigmoidf(dslow[myh]);
    float2 gf2 = make_float2(gf, gf), gs2 = make_float2(gsl, gsl);
    float2 Sf[16], Ss[16];
    #pragma unroll
    for (int j = 0; j < 16; ++j) { Sf[j] = make_float2(0.f, 0.f); Ss[j] = make_float2(0.f, 0.f); }

    // prefetch registers: tile t0=0, lane stages full row t0+n of its bh
    uint4 pq[4], pk[4], pv[4];
    float pb, pmk;
    {
        size_t ra = (size_t)(myb * SEQ + n) * DQKV + myh * DHEAD;
        #pragma unroll
        for (int s = 0; s < 4; ++s) {
            pq[s] = *(const uint4*)(qkv + ra + s * 8);
            pk[s] = *(const uint4*)(qkv + ra + DMODEL + s * 8);
            pv[s] = *(const uint4*)(qkv + ra + 2 * DMODEL + s * 8);
        }
        pb  = beta[(size_t)(myb * SEQ + n) * NH + myh];
        pmk = mask[myb * SEQ + n];
    }

    for (int t0 = 0; t0 < SEQ; t0 += SCAN_T) {
        __syncthreads();
        // ---- stage prefetched tile into LDS, fusing q/k l2norm + k*mask (in-lane)
        {
            ushort tq[32], tk[32], tv[32];
            #pragma unroll
            for (int s = 0; s < 4; ++s) {
                *(uint4*)(tq + s * 8) = pq[s];
                *(uint4*)(tk + s * 8) = pk[s];
                *(uint4*)(tv + s * 8) = pv[s];
            }
            float qv[32], kv[32];
            float sq = 0.f, sk = 0.f;
            #pragma unroll
            for (int j = 0; j < 32; ++j) {
                qv[j] = bf2f(tq[j]); sq += qv[j] * qv[j];
                kv[j] = bf2f(tk[j]); sk += kv[j] * kv[j];
            }
            float rq = 1.0f / (sqrtf(sq) + 1e-6f);
            float rk = pmk / (sqrtf(sk) + 1e-6f);
            #pragma unroll
            for (int s = 0; s < 8; ++s) {
                float4 fq, fk, fv;
                fq.x = qv[s*4+0]*rq; fq.y = qv[s*4+1]*rq; fq.z = qv[s*4+2]*rq; fq.w = qv[s*4+3]*rq;
                fk.x = kv[s*4+0]*rk; fk.y = kv[s*4+1]*rk; fk.z = kv[s*4+2]*rk; fk.w = kv[s*4+3]*rk;
                fv.x = bf2f(tv[s*4+0]); fv.y = bf2f(tv[s*4+1]); fv.z = bf2f(tv[s*4+2]); fv.w = bf2f(tv[s*4+3]);
                *(float4*)&qs[half][n][s * 4] = fq;
                *(float4*)&ks[half][n][s * 4] = fk;
                *(float4*)&vs[half][n][s * 4] = fv;
            }
            bs[half][n] = pb;
        }
        __syncthreads();

        // ---- prefetch next tile (global loads: vmcnt only, hides under compute)
        if (t0 + SCAN_T < SEQ) {
            size_t ra = (size_t)(myb * SEQ + t0 + SCAN_T + n) * DQKV + myh * DHEAD;
            #pragma unroll
            for (int s = 0; s < 4; ++s) {
                pq[s] = *(const uint4*)(qkv + ra + s * 8);
                pk[s] = *(const uint4*)(qkv + ra + DMODEL + s * 8);
                pv[s] = *(const uint4*)(qkv + ra + 2 * DMODEL + s * 8);
            }
            pb  = beta[(size_t)(myb * SEQ + t0 + SCAN_T + n) * NH + myh];
            pmk = mask[myb * SEQ + t0 + SCAN_T + n];
        }

        #pragma unroll 4
        for (int t = 0; t < SCAN_T; ++t) {
            float2 kt[16], qt[16];
            #pragma unroll
            for (int s = 0; s < 8; ++s) {
                *(float4*)&kt[s * 2] = *(const float4*)&ks[half][t][s * 4];
                *(float4*)&qt[s * 2] = *(const float4*)&qs[half][t][s * 4];
            }
            float vt = vs[half][t][n], bt = bs[half][t];

            float2 pf0 = kt[0] * Sf[0], pf1 = kt[1] * Sf[1], pf2 = kt[2] * Sf[2], pf3 = kt[3] * Sf[3];
            float2 ps0 = kt[0] * Ss[0], ps1 = kt[1] * Ss[1], ps2 = kt[2] * Ss[2], ps3 = kt[3] * Ss[3];
            #pragma unroll
            for (int j = 4; j < 16; j += 4) {
                pf0 += kt[j] * Sf[j];     pf1 += kt[j + 1] * Sf[j + 1];
                pf2 += kt[j + 2] * Sf[j + 2]; pf3 += kt[j + 3] * Sf[j + 3];
                ps0 += kt[j] * Ss[j];     ps1 += kt[j + 1] * Ss[j + 1];
                ps2 += kt[j + 2] * Ss[j + 2]; ps3 += kt[j + 3] * Ss[j + 3];
            }
            float2 pfv = (pf0 + pf1) + (pf2 + pf3);
            float2 psv = (ps0 + ps1) + (ps2 + ps3);
            float pft = pfv.x + pfv.y, pst = psv.x + psv.y;

            float cf = bt * (vt - pft), cs = bt * (vt - pst);
            float2 cf2 = make_float2(cf, cf), cs2 = make_float2(cs, cs);

            float2 o0 = make_float2(0.f, 0.f), o1 = o0, o2 = o0, o3 = o0;
            #pragma unroll
            for (int j = 0; j < 16; j += 4) {
                Sf[j] = gf2 * Sf[j] + kt[j] * cf2;         Ss[j] = gs2 * Ss[j] + kt[j] * cs2;
                Sf[j+1] = gf2 * Sf[j+1] + kt[j+1] * cf2;   Ss[j+1] = gs2 * Ss[j+1] + kt[j+1] * cs2;
                Sf[j+2] = gf2 * Sf[j+2] + kt[j+2] * cf2;   Ss[j+2] = gs2 * Ss[j+2] + kt[j+2] * cs2;
                Sf[j+3] = gf2 * Sf[j+3] + kt[j+3] * cf2;   Ss[j+3] = gs2 * Ss[j+3] + kt[j+3] * cs2;
                o0 += qt[j] * (Sf[j] + Ss[j]);
                o1 += qt[j+1] * (Sf[j+1] + Ss[j+1]);
                o2 += qt[j+2] * (Sf[j+2] + Ss[j+2]);
                o3 += qt[j+3] * (Sf[j+3] + Ss[j+3]);
            }
            float2 ov = (o0 + o1) + (o2 + o3);
            float ott = ov.x + ov.y;
            // o into q-section of qkv: row stride DQKV (both halves write their own bh)
            o[((size_t)(myb * SEQ + t0 + t)) * DQKV + myh * DHEAD + n] = f2bf(0.5f * ott);
        }
    }
}

// ---------------------------------------------------------------- masked mean-pool + l2 normalize
__global__ __launch_bounds__(384)
void pool_kernel(const float* __restrict__ x, const float* __restrict__ mask,
                 float* __restrict__ out)
{
    int b = blockIdx.x;
    int d = threadIdx.x;
    float acc = 0.f, msum = 0.f;
    for (int l = 0; l < SEQ; ++l) {
        float mk = mask[b * SEQ + l];
        acc += x[((size_t)b * SEQ + l) * DMODEL + d] * mk;
        msum += mk;
    }
    float emb = acc / fmaxf(msum, 1e-9f);
    __shared__ float red[6];
    float ss = wave_reduce_sum(emb * emb);
    int wvi = d >> 6, ln = d & 63;
    if (ln == 0) red[wvi] = ss;
    __syncthreads();
    float tot = 0.f;
    #pragma unroll
    for (int i = 0; i < 6; ++i) tot += red[i];
    float nrm = fmaxf(sqrtf(tot), 1e-12f);
    out[(size_t)b * DMODEL + d] = emb / nrm;
}

// ---------------------------------------------------------------- launch

extern "C" void kernel_launch(void* const* d_in, const int* in_sizes, int n_in,
                              void* d_out, int out_size, void* d_ws, size_t ws_size,
                              hipStream_t stream)
{
    const int*   ids   = (const int*)d_in[0];
    const float* mask  = (const float*)d_in[1];
    const float* we    = (const float*)d_in[2];
    const float* pe    = (const float*)d_in[3];
    const float* te    = (const float*)d_in[4];
    const float* elg   = (const float*)d_in[5];
    const float* elb   = (const float*)d_in[6];
    const float* Wq    = (const float*)d_in[7];
    const float* bq    = (const float*)d_in[8];
    const float* Wk    = (const float*)d_in[9];
    const float* bk    = (const float*)d_in[10];
    const float* Wv    = (const float*)d_in[11];
    const float* bv    = (const float*)d_in[12];
    const float* Wb    = (const float*)d_in[13];
    const float* dfast = (const float*)d_in[14];
    const float* dslow = (const float*)d_in[15];
    const float* Wo    = (const float*)d_in[16];
    const float* bo    = (const float*)d_in[17];
    const float* l1g   = (const float*)d_in[18];
    const float* l1b   = (const float*)d_in[19];
    const float* W1    = (const float*)d_in[20];
    const float* b1    = (const float*)d_in[21];
    const float* W2    = (const float*)d_in[22];
    const float* b2    = (const float*)d_in[23];
    const float* l2g   = (const float*)d_in[24];
    const float* l2b   = (const float*)d_in[25];
    float* out = (float*)d_out;

    // ---- workspace: 199.0 MB total (proven ceiling 202.9 MB, R4) ----
    const size_t RD = (size_t)NROWS * DMODEL;    // 12,582,912 elements
    float* x      = (float*)d_ws;                      // 50.33 MB
    float* betab  = x + RD;                            //  1.57 MB
    ushort* xb    = (ushort*)(betab + (size_t)NROWS * NH);   // 25.17 MB
    ushort* qkvb  = xb + RD;                           // 75.50 MB  [row][1152]
    ushort* ab    = qkvb + (size_t)NROWS * DQKV;       // 25.17 MB (attn out / FFN W2-out)
    ushort* WqkvT = ab + RD;                           //  5.31 MB [L][1152][384]
    ushort* WoT   = WqkvT + (size_t)NLAYER * DQKV * DMODEL;  // 1.77 MB
    ushort* W1T   = WoT + (size_t)NLAYER * DMODEL * DMODEL;  // 7.08 MB [L][1536][384]
    ushort* W2T   = W1T + (size_t)NLAYER * DMODEL * DFFN;    // 7.08 MB [L][384][1536]
    float* biasqkv = (float*)(W2T + (size_t)NLAYER * DFFN * DMODEL); // 27 KB

    dim3 blk256(256);
    dim3 rowsGrid(NROWS / 4);
    dim3 gemmGrid_QKV(NROWS / 128, DQKV / 128);      // (256, 9)
    dim3 gemmGrid_D(NROWS / 128, DMODEL / 128);      // (256, 3)
    dim3 gemmGrid_C1(FFN_CHUNK / 128, DFFN / 128);   // (128, 12)
    dim3 gemmGrid_C2(FFN_CHUNK / 128, DMODEL / 128); // (128, 3)
    dim3 chunkRows(FFN_CHUNK / 4);
    dim3 scanGrid(BATCH * NH / 2);                   // 384 single-wave blocks, 2 bh each

    const size_t lsQKV = (size_t)DQKV * DMODEL;
    convT_kernel<<<dim3(12, 12, NLAYER), blk256, 0, stream>>>(Wq, WqkvT, DMODEL, DMODEL, lsQKV, 0);
    convT_kernel<<<dim3(12, 12, NLAYER), blk256, 0, stream>>>(Wk, WqkvT, DMODEL, DMODEL, lsQKV, DMODEL);
    convT_kernel<<<dim3(12, 12, NLAYER), blk256, 0, stream>>>(Wv, WqkvT, DMODEL, DMODEL, lsQKV, 2*DMODEL);
    convT_kernel<<<dim3(12, 12, NLAYER), blk256, 0, stream>>>(Wo, WoT, DMODEL, DMODEL, (size_t)DMODEL*DMODEL, 0);
    convT_kernel<<<dim3(12, 48, NLAYER), blk256, 0, stream>>>(W1, W1T, DMODEL, DFFN, (size_t)DMODEL*DFFN, 0);
    convT_kernel<<<dim3(48, 12, NLAYER), blk256, 0, stream>>>(W2, W2T, DFFN, DMODEL, (size_t)DFFN*DMODEL, 0);
    biascat_kernel<<<dim3(NLAYER), dim3(384), 0, stream>>>(bq, bk, bv, biasqkv);

    embed_ln_kernel<<<rowsGrid, blk256, 0, stream>>>(ids, we, pe, te, elg, elb, x, xb);

    for (int i = 0; i < NLAYER; ++i) {
        const ushort* WqkvT_i = WqkvT + (size_t)i * lsQKV;
        const ushort* WoT_i   = WoT + (size_t)i * DMODEL * DMODEL;
        const float*  Wb_i    = Wb  + (size_t)i * DMODEL * NH;
        const ushort* W1T_i   = W1T + (size_t)i * DMODEL * DFFN;
        const ushort* W2T_i   = W2T + (size_t)i * DFFN * DMODEL;

        gemm_mfma<ushort><<<gemmGrid_QKV, blk256, 0, stream>>>(xb, WqkvT_i, biasqkv + (size_t)i * DQKV,
                                                               qkvb, NROWS, DQKV, DMODEL, DMODEL, 0);
        beta_kernel<<<rowsGrid, blk256, 0, stream>>>(xb, Wb_i, mask, betab);
        // q/k l2norm + k*mask fused into scan staging; o overwrites q-section of qkvb
        scan_kernel<<<scanGrid, dim3(64), 0, stream>>>(qkvb, betab, mask,
                                                       dfast + i * NH, dslow + i * NH, qkvb);
        // Wo GEMM reads strided o (Astride = DQKV)
        gemm_mfma<ushort><<<gemmGrid_D, blk256, 0, stream>>>(qkvb, WoT_i, bo + i * DMODEL, ab,
                                                             NROWS, DMODEL, DMODEL, DQKV, 0);
        add_ln_kernel<<<rowsGrid, blk256, 0, stream>>>(x, xb, ab, l1g + i * DMODEL, l1b + i * DMODEL);

        // FFN in 2 chunks. Chunks are SEQUENTIAL, so the h buffer is reused:
        // h -> qkvb front (25.17 MB, qkvb dead after Wo GEMM), W2-out -> ab
        // (dead after add_ln1; two chunks exactly fill ab).
        for (int c = 0; c < NROWS / FFN_CHUNK; ++c) {
            const ushort* xc = xb + (size_t)c * FFN_CHUNK * DMODEL;
            ushort* hbuf  = qkvb;                                   // reused per chunk
            ushort* w2out = ab + (size_t)c * FFN_CHUNK * DMODEL;
            gemm_mfma<ushort><<<gemmGrid_C1, blk256, 0, stream>>>(xc, W1T_i, b1 + i * DFFN, hbuf,
                                                                  FFN_CHUNK, DFFN, DMODEL, DMODEL, 1);
            gemm_mfma<ushort><<<gemmGrid_C2, blk256, 0, stream>>>(hbuf, W2T_i, b2 + i * DMODEL, w2out,
                                                                  FFN_CHUNK, DMODEL, DFFN, DFFN, 0);
            add_ln_kernel<<<chunkRows, blk256, 0, stream>>>(x + (size_t)c * FFN_CHUNK * DMODEL,
                                                            xb + (size_t)c * FFN_CHUNK * DMODEL, w2out,
                                                            l2g + i * DMODEL, l2b + i * DMODEL);
        }
    }

    pool_kernel<<<dim3(BATCH), dim3(384), 0, stream>>>(x, mask, out);
}

// Round 11
// 3183.295 us; speedup vs baseline: 1.2729x; 1.0496x over previous
//
#include <hip/hip_runtime.h>
#include <cstdint>
#include <cstddef>
#include <cmath>

#define NLAYER 6
#define NH 12
#define DMODEL 384
#define DHEAD 32
#define DFFN 1536
#define BATCH 64
#define SEQ 512
#define NROWS (BATCH*SEQ)   // 32768
#define DQKV 1152           // fused q|k|v row length

typedef unsigned short ushort;
typedef __attribute__((ext_vector_type(8))) short bf16x8;   // 8 bf16 = 4 VGPRs
typedef __attribute__((ext_vector_type(4))) float f32x4;

// ---------------------------------------------------------------- utilities

__device__ inline float bf2f(ushort u) {
    union { unsigned int i; float f; } c; c.i = ((unsigned int)u) << 16; return c.f;
}
__device__ inline ushort f2bf(float f) {
    union { float f; unsigned int i; } c; c.f = f;
    unsigned int i = c.i;
    unsigned int lsb = (i >> 16) & 1u;
    i += 0x7fffu + lsb;          // round-to-nearest-even
    return (ushort)(i >> 16);
}

__device__ inline float wave_reduce_sum(float v) {
    #pragma unroll
    for (int m = 32; m >= 1; m >>= 1) v += __shfl_xor(v, m, 64);
    return v;
}

__device__ inline float sigmoidf(float x) { return 1.0f / (1.0f + expf(-x)); }

__device__ inline float gelu_tanh(float x) {
    const float c = 0.7978845608028654f; // sqrt(2/pi)
    float t = tanhf(c * (x + 0.044715f * x * x * x));
    return 0.5f * x * (1.0f + t);
}

// async global->LDS, 16 bytes per lane; lds base must be wave-uniform
__device__ inline void async16(const ushort* g, ushort* l) {
    __builtin_amdgcn_global_load_lds(
        (const __attribute__((address_space(1))) unsigned int*)g,
        (__attribute__((address_space(3))) unsigned int*)l,
        16, 0, 0);
}

// ---------------------------------------------------------------- weight convert+transpose
// W fp32 [L][K][N] -> WT bf16 rows of K elements; layer stride lStride,
// dest row offset nOff (fused QKV packing).
__global__ __launch_bounds__(256)
void convT_kernel(const float* __restrict__ W, ushort* __restrict__ WT, int K, int N,
                  size_t lStride, int nOff)
{
    __shared__ float t[32][33];
    int k0 = blockIdx.x * 32, n0 = blockIdx.y * 32, L = blockIdx.z;
    const float* Wl = W + (size_t)L * K * N;
    ushort* WTl = WT + (size_t)L * lStride;
    int tx = threadIdx.x & 31, ty = threadIdx.x >> 5;   // 32 x 8
    #pragma unroll
    for (int i = 0; i < 4; ++i)
        t[ty + 8 * i][tx] = Wl[(size_t)(k0 + ty + 8 * i) * N + n0 + tx];
    __syncthreads();
    #pragma unroll
    for (int i = 0; i < 4; ++i)
        WTl[(size_t)(nOff + n0 + ty + 8 * i) * K + k0 + tx] = f2bf(t[tx][ty + 8 * i]);
}

// ---------------------------------------------------------------- fused qkv bias concat: [L][1152]
__global__ __launch_bounds__(384)
void biascat_kernel(const float* __restrict__ bq, const float* __restrict__ bk,
                    const float* __restrict__ bv, float* __restrict__ dst)
{
    int L = blockIdx.x, d = threadIdx.x;
    dst[(size_t)L * DQKV + d]             = bq[(size_t)L * DMODEL + d];
    dst[(size_t)L * DQKV + DMODEL + d]    = bk[(size_t)L * DMODEL + d];
    dst[(size_t)L * DQKV + 2*DMODEL + d]  = bv[(size_t)L * DMODEL + d];
}

// ---------------------------------------------------------------- embedding + LN (writes fp32 x and bf16 xb)
__global__ __launch_bounds__(256)
void embed_ln_kernel(const int* __restrict__ ids, const float* __restrict__ we,
                     const float* __restrict__ pe, const float* __restrict__ te,
                     const float* __restrict__ g, const float* __restrict__ bb,
                     float* __restrict__ x, ushort* __restrict__ xb)
{
    int row = blockIdx.x * 4 + (threadIdx.x >> 6);
    int lane = threadIdx.x & 63;
    int l = row & (SEQ - 1);
    int id = ids[row];
    float vals[6];
    float s = 0.f;
    #pragma unroll
    for (int t = 0; t < 6; ++t) {
        int d = lane + 64 * t;
        float v = we[(size_t)id * DMODEL + d] + pe[(size_t)l * DMODEL + d] + te[d];
        vals[t] = v; s += v;
    }
    s = wave_reduce_sum(s);
    float m = s * (1.0f / DMODEL);
    float s2 = 0.f;
    #pragma unroll
    for (int t = 0; t < 6; ++t) { float dd = vals[t] - m; s2 += dd * dd; }
    s2 = wave_reduce_sum(s2);
    float rs = rsqrtf(s2 * (1.0f / DMODEL) + 1e-12f);
    #pragma unroll
    for (int t = 0; t < 6; ++t) {
        int d = lane + 64 * t;
        float val = (vals[t] - m) * rs * g[d] + bb[d];
        x[(size_t)row * DMODEL + d] = val;
        xb[(size_t)row * DMODEL + d] = f2bf(val);
    }
}

// ---------------------------------------------------------------- residual add + LN (separate residual buffer r)
__global__ __launch_bounds__(256)
void add_ln_kernel(float* x, ushort* __restrict__ xb, const ushort* __restrict__ r,
                   const float* __restrict__ g, const float* __restrict__ bb)
{
    int row = blockIdx.x * 4 + (threadIdx.x >> 6);
    int lane = threadIdx.x & 63;
    float vals[6];
    float s = 0.f;
    #pragma unroll
    for (int t = 0; t < 6; ++t) {
        int d = lane + 64 * t;
        size_t idx = (size_t)row * DMODEL + d;
        float v = x[idx] + bf2f(r[idx]);
        vals[t] = v; s += v;
    }
    s = wave_reduce_sum(s);
    float m = s * (1.0f / DMODEL);
    float s2 = 0.f;
    #pragma unroll
    for (int t = 0; t < 6; ++t) { float dd = vals[t] - m; s2 += dd * dd; }
    s2 = wave_reduce_sum(s2);
    float rs = rsqrtf(s2 * (1.0f / DMODEL) + 1e-12f);
    #pragma unroll
    for (int t = 0; t < 6; ++t) {
        int d = lane + 64 * t;
        size_t idx = (size_t)row * DMODEL + d;
        float val = (vals[t] - m) * rs * g[d] + bb[d];
        x[idx] = val;
        xb[idx] = f2bf(val);
    }
}

// ---------------------------------------------------------------- residual add + LN, residual IN xb (read+rewrite in place)
// Used for the FFN: W2 wrote its output into xb (dead after the W1 GEMM).
// Per thread, per index: read xb[idx] (w2out), later write xb[idx] (new LN
// bf16). Same-thread same-address; no cross-thread aliasing; no __restrict__
// on xb/x so the compiler keeps the program order.
__global__ __launch_bounds__(256)
void add_ln_ip_kernel(float* x, ushort* xb,
                      const float* __restrict__ g, const float* __restrict__ bb)
{
    int row = blockIdx.x * 4 + (threadIdx.x >> 6);
    int lane = threadIdx.x & 63;
    float vals[6];
    float s = 0.f;
    #pragma unroll
    for (int t = 0; t < 6; ++t) {
        int d = lane + 64 * t;
        size_t idx = (size_t)row * DMODEL + d;
        float v = x[idx] + bf2f(xb[idx]);
        vals[t] = v; s += v;
    }
    s = wave_reduce_sum(s);
    float m = s * (1.0f / DMODEL);
    float s2 = 0.f;
    #pragma unroll
    for (int t = 0; t < 6; ++t) { float dd = vals[t] - m; s2 += dd * dd; }
    s2 = wave_reduce_sum(s2);
    float rs = rsqrtf(s2 * (1.0f / DMODEL) + 1e-12f);
    #pragma unroll
    for (int t = 0; t < 6; ++t) {
        int d = lane + 64 * t;
        size_t idx = (size_t)row * DMODEL + d;
        float val = (vals[t] - m) * rs * g[d] + bb[d];
        x[idx] = val;
        xb[idx] = f2bf(val);
    }
}

// ---------------------------------------------------------------- bf16 MFMA GEMM, async-staged  [verified R7]
// A row stride Astride (elements) may differ from K (strided o-section reads).
template<typename TC>
__global__ __launch_bounds__(256)
void gemm_mfma(const ushort* __restrict__ A, const ushort* __restrict__ WT,
               const float* __restrict__ bias, TC* __restrict__ C,
               int M, int N, int K, int Astride, int act)
{
    __shared__ __align__(16) ushort As[128 * 64];   // 16 KB
    __shared__ __align__(16) ushort Bs[128 * 64];   // 16 KB
    int tid = threadIdx.x;
    int lane = tid & 63, wv = tid >> 6;
    int waveM = wv >> 1, waveN = wv & 1;
    int lm = lane & 15, quad = lane >> 4;
    int row0 = blockIdx.x * 128, col0 = blockIdx.y * 128;
    int srow = lane >> 3, sseg = lane & 7;          // staging: 8 rows x 8 segs

    f32x4 acc[4][4] = {};

    for (int k0 = 0; k0 < K; k0 += 64) {
        __syncthreads();
        #pragma unroll
        for (int i = 0; i < 4; ++i) {
            int r = wv * 32 + i * 8 + srow;
            int sg = sseg ^ (r & 7);
            async16(A  + (size_t)(row0 + r) * Astride + k0 + sg * 8, &As[(wv * 32 + i * 8) * 64]);
            async16(WT + (size_t)(col0 + r) * K + k0 + sg * 8, &Bs[(wv * 32 + i * 8) * 64]);
        }
        __syncthreads();

        #pragma unroll
        for (int ks = 0; ks < 2; ++ks) {
            int physA = ((ks * 4 + quad) ^ (lm & 7)) * 8;
            bf16x8 af[4], bf[4];
            #pragma unroll
            for (int mt = 0; mt < 4; ++mt)
                af[mt] = *(const bf16x8*)&As[(waveM * 64 + mt * 16 + lm) * 64 + physA];
            #pragma unroll
            for (int nt = 0; nt < 4; ++nt)
                bf[nt] = *(const bf16x8*)&Bs[(waveN * 64 + nt * 16 + lm) * 64 + physA];
            #pragma unroll
            for (int mt = 0; mt < 4; ++mt)
                #pragma unroll
                for (int nt = 0; nt < 4; ++nt)
                    acc[mt][nt] = __builtin_amdgcn_mfma_f32_16x16x32_bf16(af[mt], bf[nt], acc[mt][nt], 0, 0, 0);
        }
    }

    #pragma unroll
    for (int mt = 0; mt < 4; ++mt) {
        #pragma unroll
        for (int nt = 0; nt < 4; ++nt) {
            int col = col0 + waveN * 64 + nt * 16 + lm;
            float bv = bias[col];
            #pragma unroll
            for (int r = 0; r < 4; ++r) {
                int row = row0 + waveM * 64 + mt * 16 + quad * 4 + r;
                float val = acc[mt][nt][r] + bv;
                if (act == 1) val = gelu_tanh(gelu_tanh(val));
                if constexpr (sizeof(TC) == 2)
                    C[(size_t)row * N + col] = f2bf(val);
                else
                    C[(size_t)row * N + col] = val;
            }
        }
    }
}

// ---------------------------------------------------------------- beta: wave per row, coalesced bf16 x  [verified R7]
__global__ __launch_bounds__(256)
void beta_kernel(const ushort* __restrict__ xb, const float* __restrict__ Wb,
                 const float* __restrict__ mask, float* __restrict__ beta)
{
    int row = blockIdx.x * 4 + (threadIdx.x >> 6);
    int lane = threadIdx.x & 63;
    float xr[6];
    #pragma unroll
    for (int t = 0; t < 6; ++t) xr[t] = bf2f(xb[(size_t)row * DMODEL + lane + 64 * t]);
    float mine = 0.f;
    #pragma unroll
    for (int h = 0; h < NH; ++h) {
        float p = 0.f;
        #pragma unroll
        for (int t = 0; t < 6; ++t) p += xr[t] * Wb[(size_t)(lane + 64 * t) * NH + h];
        p = wave_reduce_sum(p);
        if (lane == h) mine = p;
    }
    if (lane < NH) beta[(size_t)row * NH + lane] = sigmoidf(mine) * mask[row];
}

// ---------------------------------------------------------------- delta-rule scan v7 [BEST MEASURED: 216 us, R4/R10]
// Wave serves 2 (b,h): half = lane>>5 picks bh, n = lane&31 = state column.
// Lane owns the FULL 32-deep k state for column n (float2-packed). All math
// in-lane: no shfl/bpermute in the loop. Staging: lane stages full row t0+n
// of its bh with fused q/k l2norm + k*mask. Next tile prefetched to regs
// (vmcnt only). Per-step LDS reads: k/q rows are half-wave broadcasts;
// vs[t][n] stride-1 -- conflict-free.
// o writes into the q-section of qkv (rows < t0+32; prefetch reads >= t0+32).
// Session ledger: v6 (k-split + shfl) 208, v7 216, v8 (src pipeline) 230,
// v9 (2-step fusion) 260, v10 (chunk-parallel 3-phase) ~324/layer -- every
// restructuring of the VALU scan lands ~1000 cyc/step (parallelism
// elasticity measured ~1.33x at 4x occupancy); v7 kept as local optimum.
#define SCAN_T 32
#define SPAD 36
__global__ __launch_bounds__(64)
void scan_kernel(const ushort* __restrict__ qkv, const float* __restrict__ beta,
                 const float* __restrict__ mask,
                 const float* __restrict__ dfast, const float* __restrict__ dslow,
                 ushort* __restrict__ o)
{
    __shared__ __align__(16) float qs[2][SCAN_T][SPAD];
    __shared__ __align__(16) float ks[2][SCAN_T][SPAD];
    __shared__ __align__(16) float vs[2][SCAN_T][SPAD];
    __shared__ float bs[2][SCAN_T];

    int gw = blockIdx.x;
    int lane = threadIdx.x;
    int half = lane >> 5, n = lane & 31;
    int bh = gw * 2 + half;
    int myb = bh / NH, myh = bh % NH;

    float gf = sigmoidf(dfast[myh]);
    float gsl = sigmoidf(dslow[myh]);
    float2 gf2 = make_float2(gf, gf), gs2 = make_float2(gsl, gsl);
    float2 Sf[16], Ss[16];
    #pragma unroll
    for (int j = 0; j < 16; ++j) { Sf[j] = make_float2(0.f, 0.f); Ss[j] = make_float2(0.f, 0.f); }

    // prefetch registers: tile t0=0, lane stages full row t0+n of its bh
    uint4 pq[4], pk[4], pv[4];
    float pb, pmk;
    {
        size_t ra = (size_t)(myb * SEQ + n) * DQKV + myh * DHEAD;
        #pragma unroll
        for (int s = 0; s < 4; ++s) {
            pq[s] = *(const uint4*)(qkv + ra + s * 8);
            pk[s] = *(const uint4*)(qkv + ra + DMODEL + s * 8);
            pv[s] = *(const uint4*)(qkv + ra + 2 * DMODEL + s * 8);
        }
        pb  = beta[(size_t)(myb * SEQ + n) * NH + myh];
        pmk = mask[myb * SEQ + n];
    }

    for (int t0 = 0; t0 < SEQ; t0 += SCAN_T) {
        __syncthreads();
        // ---- stage prefetched tile into LDS, fusing q/k l2norm + k*mask (in-lane)
        {
            ushort tq[32], tk[32], tv[32];
            #pragma unroll
            for (int s = 0; s < 4; ++s) {
                *(uint4*)(tq + s * 8) = pq[s];
                *(uint4*)(tk + s * 8) = pk[s];
                *(uint4*)(tv + s * 8) = pv[s];
            }
            float qv[32], kv[32];
            float sq = 0.f, sk = 0.f;
            #pragma unroll
            for (int j = 0; j < 32; ++j) {
                qv[j] = bf2f(tq[j]); sq += qv[j] * qv[j];
                kv[j] = bf2f(tk[j]); sk += kv[j] * kv[j];
            }
            float rq = 1.0f / (sqrtf(sq) + 1e-6f);
            float rk = pmk / (sqrtf(sk) + 1e-6f);
            #pragma unroll
            for (int s = 0; s < 8; ++s) {
                float4 fq, fk, fv;
                fq.x = qv[s*4+0]*rq; fq.y = qv[s*4+1]*rq; fq.z = qv[s*4+2]*rq; fq.w = qv[s*4+3]*rq;
                fk.x = kv[s*4+0]*rk; fk.y = kv[s*4+1]*rk; fk.z = kv[s*4+2]*rk; fk.w = kv[s*4+3]*rk;
                fv.x = bf2f(tv[s*4+0]); fv.y = bf2f(tv[s*4+1]); fv.z = bf2f(tv[s*4+2]); fv.w = bf2f(tv[s*4+3]);
                *(float4*)&qs[half][n][s * 4] = fq;
                *(float4*)&ks[half][n][s * 4] = fk;
                *(float4*)&vs[half][n][s * 4] = fv;
            }
            bs[half][n] = pb;
        }
        __syncthreads();

        // ---- prefetch next tile (global loads: vmcnt only, hides under compute)
        if (t0 + SCAN_T < SEQ) {
            size_t ra = (size_t)(myb * SEQ + t0 + SCAN_T + n) * DQKV + myh * DHEAD;
            #pragma unroll
            for (int s = 0; s < 4; ++s) {
                pq[s] = *(const uint4*)(qkv + ra + s * 8);
                pk[s] = *(const uint4*)(qkv + ra + DMODEL + s * 8);
                pv[s] = *(const uint4*)(qkv + ra + 2 * DMODEL + s * 8);
            }
            pb  = beta[(size_t)(myb * SEQ + t0 + SCAN_T + n) * NH + myh];
            pmk = mask[myb * SEQ + t0 + SCAN_T + n];
        }

        #pragma unroll 4
        for (int t = 0; t < SCAN_T; ++t) {
            float2 kt[16], qt[16];
            #pragma unroll
            for (int s = 0; s < 8; ++s) {
                *(float4*)&kt[s * 2] = *(const float4*)&ks[half][t][s * 4];
                *(float4*)&qt[s * 2] = *(const float4*)&qs[half][t][s * 4];
            }
            float vt = vs[half][t][n], bt = bs[half][t];

            float2 pf0 = kt[0] * Sf[0], pf1 = kt[1] * Sf[1], pf2 = kt[2] * Sf[2], pf3 = kt[3] * Sf[3];
            float2 ps0 = kt[0] * Ss[0], ps1 = kt[1] * Ss[1], ps2 = kt[2] * Ss[2], ps3 = kt[3] * Ss[3];
            #pragma unroll
            for (int j = 4; j < 16; j += 4) {
                pf0 += kt[j] * Sf[j];     pf1 += kt[j + 1] * Sf[j + 1];
                pf2 += kt[j + 2] * Sf[j + 2]; pf3 += kt[j + 3] * Sf[j + 3];
                ps0 += kt[j] * Ss[j];     ps1 += kt[j + 1] * Ss[j + 1];
                ps2 += kt[j + 2] * Ss[j + 2]; ps3 += kt[j + 3] * Ss[j + 3];
            }
            float2 pfv = (pf0 + pf1) + (pf2 + pf3);
            float2 psv = (ps0 + ps1) + (ps2 + ps3);
            float pft = pfv.x + pfv.y, pst = psv.x + psv.y;

            float cf = bt * (vt - pft), cs = bt * (vt - pst);
            float2 cf2 = make_float2(cf, cf), cs2 = make_float2(cs, cs);

            float2 o0 = make_float2(0.f, 0.f), o1 = o0, o2 = o0, o3 = o0;
            #pragma unroll
            for (int j = 0; j < 16; j += 4) {
                Sf[j] = gf2 * Sf[j] + kt[j] * cf2;         Ss[j] = gs2 * Ss[j] + kt[j] * cs2;
                Sf[j+1] = gf2 * Sf[j+1] + kt[j+1] * cf2;   Ss[j+1] = gs2 * Ss[j+1] + kt[j+1] * cs2;
                Sf[j+2] = gf2 * Sf[j+2] + kt[j+2] * cf2;   Ss[j+2] = gs2 * Ss[j+2] + kt[j+2] * cs2;
                Sf[j+3] = gf2 * Sf[j+3] + kt[j+3] * cf2;   Ss[j+3] = gs2 * Ss[j+3] + kt[j+3] * cs2;
                o0 += qt[j] * (Sf[j] + Ss[j]);
                o1 += qt[j+1] * (Sf[j+1] + Ss[j+1]);
                o2 += qt[j+2] * (Sf[j+2] + Ss[j+2]);
                o3 += qt[j+3] * (Sf[j+3] + Ss[j+3]);
            }
            float2 ov = (o0 + o1) + (o2 + o3);
            float ott = ov.x + ov.y;
            // o into q-section of qkv: row stride DQKV (both halves write their own bh)
            o[((size_t)(myb * SEQ + t0 + t)) * DQKV + myh * DHEAD + n] = f2bf(0.5f * ott);
        }
    }
}

// ---------------------------------------------------------------- masked mean-pool + l2 normalize
__global__ __launch_bounds__(384)
void pool_kernel(const float* __restrict__ x, const float* __restrict__ mask,
                 float* __restrict__ out)
{
    int b = blockIdx.x;
    int d = threadIdx.x;
    float acc = 0.f, msum = 0.f;
    for (int l = 0; l < SEQ; ++l) {
        float mk = mask[b * SEQ + l];
        acc += x[((size_t)b * SEQ + l) * DMODEL + d] * mk;
        msum += mk;
    }
    float emb = acc / fmaxf(msum, 1e-9f);
    __shared__ float red[6];
    float ss = wave_reduce_sum(emb * emb);
    int wvi = d >> 6, ln = d & 63;
    if (ln == 0) red[wvi] = ss;
    __syncthreads();
    float tot = 0.f;
    #pragma unroll
    for (int i = 0; i < 6; ++i) tot += red[i];
    float nrm = fmaxf(sqrtf(tot), 1e-12f);
    out[(size_t)b * DMODEL + d] = emb / nrm;
}

// ---------------------------------------------------------------- launch

extern "C" void kernel_launch(void* const* d_in, const int* in_sizes, int n_in,
                              void* d_out, int out_size, void* d_ws, size_t ws_size,
                              hipStream_t stream)
{
    const int*   ids   = (const int*)d_in[0];
    const float* mask  = (const float*)d_in[1];
    const float* we    = (const float*)d_in[2];
    const float* pe    = (const float*)d_in[3];
    const float* te    = (const float*)d_in[4];
    const float* elg   = (const float*)d_in[5];
    const float* elb   = (const float*)d_in[6];
    const float* Wq    = (const float*)d_in[7];
    const float* bq    = (const float*)d_in[8];
    const float* Wk    = (const float*)d_in[9];
    const float* bk    = (const float*)d_in[10];
    const float* Wv    = (const float*)d_in[11];
    const float* bv    = (const float*)d_in[12];
    const float* Wb    = (const float*)d_in[13];
    const float* dfast = (const float*)d_in[14];
    const float* dslow = (const float*)d_in[15];
    const float* Wo    = (const float*)d_in[16];
    const float* bo    = (const float*)d_in[17];
    const float* l1g   = (const float*)d_in[18];
    const float* l1b   = (const float*)d_in[19];
    const float* W1    = (const float*)d_in[20];
    const float* b1    = (const float*)d_in[21];
    const float* W2    = (const float*)d_in[22];
    const float* b2    = (const float*)d_in[23];
    const float* l2g   = (const float*)d_in[24];
    const float* l2b   = (const float*)d_in[25];
    float* out = (float*)d_out;

    // ---- workspace: 199.0 MB total (proven ceiling 202.9 MB, R4) ----
    const size_t RD = (size_t)NROWS * DMODEL;    // 12,582,912 elements
    float* x      = (float*)d_ws;                      // 50.33 MB
    float* betab  = x + RD;                            //  1.57 MB
    ushort* xb    = (ushort*)(betab + (size_t)NROWS * NH);   // 25.17 MB
    ushort* qkvb  = xb + RD;                           // 75.50 MB  [row][1152]
    ushort* ab    = qkvb + (size_t)NROWS * DQKV;       // 25.17 MB (attn out; FFN: tail of h)
    ushort* WqkvT = ab + RD;                           //  5.31 MB [L][1152][384]
    ushort* WoT   = WqkvT + (size_t)NLAYER * DQKV * DMODEL;  // 1.77 MB
    ushort* W1T   = WoT + (size_t)NLAYER * DMODEL * DMODEL;  // 7.08 MB [L][1536][384]
    ushort* W2T   = W1T + (size_t)NLAYER * DMODEL * DFFN;    // 7.08 MB [L][384][1536]
    float* biasqkv = (float*)(W2T + (size_t)NLAYER * DFFN * DMODEL); // 27 KB

    dim3 blk256(256);
    dim3 rowsGrid(NROWS / 4);
    dim3 gemmGrid_QKV(NROWS / 128, DQKV / 128);      // (256, 9)
    dim3 gemmGrid_D(NROWS / 128, DMODEL / 128);      // (256, 3)
    dim3 gemmGrid_F1(NROWS / 128, DFFN / 128);       // (256, 12) unchunked
    dim3 gemmGrid_F2(NROWS / 128, DMODEL / 128);     // (256, 3)  unchunked
    dim3 scanGrid(BATCH * NH / 2);                   // 384 single-wave blocks, 2 bh each

    const size_t lsQKV = (size_t)DQKV * DMODEL;
    convT_kernel<<<dim3(12, 12, NLAYER), blk256, 0, stream>>>(Wq, WqkvT, DMODEL, DMODEL, lsQKV, 0);
    convT_kernel<<<dim3(12, 12, NLAYER), blk256, 0, stream>>>(Wk, WqkvT, DMODEL, DMODEL, lsQKV, DMODEL);
    convT_kernel<<<dim3(12, 12, NLAYER), blk256, 0, stream>>>(Wv, WqkvT, DMODEL, DMODEL, lsQKV, 2*DMODEL);
    convT_kernel<<<dim3(12, 12, NLAYER), blk256, 0, stream>>>(Wo, WoT, DMODEL, DMODEL, (size_t)DMODEL*DMODEL, 0);
    convT_kernel<<<dim3(12, 48, NLAYER), blk256, 0, stream>>>(W1, W1T, DMODEL, DFFN, (size_t)DMODEL*DFFN, 0);
    convT_kernel<<<dim3(48, 12, NLAYER), blk256, 0, stream>>>(W2, W2T, DFFN, DMODEL, (size_t)DFFN*DMODEL, 0);
    biascat_kernel<<<dim3(NLAYER), dim3(384), 0, stream>>>(bq, bk, bv, biasqkv);

    embed_ln_kernel<<<rowsGrid, blk256, 0, stream>>>(ids, we, pe, te, elg, elb, x, xb);

    for (int i = 0; i < NLAYER; ++i) {
        const ushort* WqkvT_i = WqkvT + (size_t)i * lsQKV;
        const ushort* WoT_i   = WoT + (size_t)i * DMODEL * DMODEL;
        const float*  Wb_i    = Wb  + (size_t)i * DMODEL * NH;
        const ushort* W1T_i   = W1T + (size_t)i * DMODEL * DFFN;
        const ushort* W2T_i   = W2T + (size_t)i * DFFN * DMODEL;

        gemm_mfma<ushort><<<gemmGrid_QKV, blk256, 0, stream>>>(xb, WqkvT_i, biasqkv + (size_t)i * DQKV,
                                                               qkvb, NROWS, DQKV, DMODEL, DMODEL, 0);
        beta_kernel<<<rowsGrid, blk256, 0, stream>>>(xb, Wb_i, mask, betab);
        // q/k l2norm + k*mask fused into scan staging; o overwrites q-section of qkvb
        scan_kernel<<<scanGrid, dim3(64), 0, stream>>>(qkvb, betab, mask,
                                                       dfast + i * NH, dslow + i * NH, qkvb);
        // Wo GEMM reads strided o (Astride = DQKV)
        gemm_mfma<ushort><<<gemmGrid_D, blk256, 0, stream>>>(qkvb, WoT_i, bo + i * DMODEL, ab,
                                                             NROWS, DMODEL, DMODEL, DQKV, 0);
        add_ln_kernel<<<rowsGrid, blk256, 0, stream>>>(x, xb, ab, l1g + i * DMODEL, l1b + i * DMODEL);

        // FFN UNCHUNKED (R11): h spans qkvb+ab -- contiguous, exactly
        // 32768*1536*2B = 100,663,296 B (qkvb 75.50 + ab 25.17, both dead:
        // qkvb after the Wo GEMM, ab after add_ln1). W2-out -> xb (dead after
        // the W1 GEMM consumed it; its LN1 content lives on in fp32 x).
        // add_ln_ip reads the residual from xb and rewrites xb with the new
        // LN output for the next layer.
        {
            ushort* hbuf = qkvb;   // 100.66 MB window (qkvb..ab end)
            gemm_mfma<ushort><<<gemmGrid_F1, blk256, 0, stream>>>(xb, W1T_i, b1 + i * DFFN, hbuf,
                                                                  NROWS, DFFN, DMODEL, DMODEL, 1);
            gemm_mfma<ushort><<<gemmGrid_F2, blk256, 0, stream>>>(hbuf, W2T_i, b2 + i * DMODEL, xb,
                                                                  NROWS, DMODEL, DFFN, DFFN, 0);
            add_ln_ip_kernel<<<rowsGrid, blk256, 0, stream>>>(x, xb, l2g + i * DMODEL, l2b + i * DMODEL);
        }
    }

    pool_kernel<<<dim3(BATCH), dim3(384), 0, stream>>>(x, mask, out);
}

// Round 12
// 3017.213 us; speedup vs baseline: 1.3429x; 1.0550x over previous
//
#include <hip/hip_runtime.h>
#include <cstdint>
#include <cstddef>
#include <cmath>

#define NLAYER 6
#define NH 12
#define DMODEL 384
#define DHEAD 32
#define DFFN 1536
#define BATCH 64
#define SEQ 512
#define NROWS (BATCH*SEQ)   // 32768
#define DQKV 1152           // fused q|k|v row length

typedef unsigned short ushort;
typedef __attribute__((ext_vector_type(8))) short bf16x8;   // 8 bf16 = 4 VGPRs
typedef __attribute__((ext_vector_type(4))) float f32x4;

// ---------------------------------------------------------------- utilities

__device__ inline float bf2f(ushort u) {
    union { unsigned int i; float f; } c; c.i = ((unsigned int)u) << 16; return c.f;
}
__device__ inline ushort f2bf(float f) {
    union { float f; unsigned int i; } c; c.f = f;
    unsigned int i = c.i;
    unsigned int lsb = (i >> 16) & 1u;
    i += 0x7fffu + lsb;          // round-to-nearest-even
    return (ushort)(i >> 16);
}

__device__ inline float wave_reduce_sum(float v) {
    #pragma unroll
    for (int m = 32; m >= 1; m >>= 1) v += __shfl_xor(v, m, 64);
    return v;
}

__device__ inline float sigmoidf(float x) { return 1.0f / (1.0f + expf(-x)); }

// fast exp-based tanh-gelu (R12): libm tanhf is ~70 VALU ops; this is ~8.
// tanh(y) = 1 - 2/(e^{2y}+1); limits correct at +/-inf; |err| ~1e-6.
__device__ inline float gelu_tanh(float x) {
    const float c = 0.7978845608028654f; // sqrt(2/pi)
    float y = c * (x + 0.044715f * x * x * x);
    float e = __expf(2.0f * y);
    float t = 1.0f - 2.0f * __builtin_amdgcn_rcpf(e + 1.0f);
    return 0.5f * x * (1.0f + t);
}

// async global->LDS, 16 bytes per lane; lds base must be wave-uniform
__device__ inline void async16(const ushort* g, ushort* l) {
    __builtin_amdgcn_global_load_lds(
        (const __attribute__((address_space(1))) unsigned int*)g,
        (__attribute__((address_space(3))) unsigned int*)l,
        16, 0, 0);
}

// ---------------------------------------------------------------- weight convert+transpose
// W fp32 [L][K][N] -> WT bf16 rows of K elements; layer stride lStride,
// dest row offset nOff (fused QKV packing).
__global__ __launch_bounds__(256)
void convT_kernel(const float* __restrict__ W, ushort* __restrict__ WT, int K, int N,
                  size_t lStride, int nOff)
{
    __shared__ float t[32][33];
    int k0 = blockIdx.x * 32, n0 = blockIdx.y * 32, L = blockIdx.z;
    const float* Wl = W + (size_t)L * K * N;
    ushort* WTl = WT + (size_t)L * lStride;
    int tx = threadIdx.x & 31, ty = threadIdx.x >> 5;   // 32 x 8
    #pragma unroll
    for (int i = 0; i < 4; ++i)
        t[ty + 8 * i][tx] = Wl[(size_t)(k0 + ty + 8 * i) * N + n0 + tx];
    __syncthreads();
    #pragma unroll
    for (int i = 0; i < 4; ++i)
        WTl[(size_t)(nOff + n0 + ty + 8 * i) * K + k0 + tx] = f2bf(t[tx][ty + 8 * i]);
}

// ---------------------------------------------------------------- fused qkv bias concat: [L][1152]
__global__ __launch_bounds__(384)
void biascat_kernel(const float* __restrict__ bq, const float* __restrict__ bk,
                    const float* __restrict__ bv, float* __restrict__ dst)
{
    int L = blockIdx.x, d = threadIdx.x;
    dst[(size_t)L * DQKV + d]             = bq[(size_t)L * DMODEL + d];
    dst[(size_t)L * DQKV + DMODEL + d]    = bk[(size_t)L * DMODEL + d];
    dst[(size_t)L * DQKV + 2*DMODEL + d]  = bv[(size_t)L * DMODEL + d];
}

// ---------------------------------------------------------------- embedding + LN (writes fp32 x and bf16 xb)
__global__ __launch_bounds__(256)
void embed_ln_kernel(const int* __restrict__ ids, const float* __restrict__ we,
                     const float* __restrict__ pe, const float* __restrict__ te,
                     const float* __restrict__ g, const float* __restrict__ bb,
                     float* __restrict__ x, ushort* __restrict__ xb)
{
    int row = blockIdx.x * 4 + (threadIdx.x >> 6);
    int lane = threadIdx.x & 63;
    int l = row & (SEQ - 1);
    int id = ids[row];
    float vals[6];
    float s = 0.f;
    #pragma unroll
    for (int t = 0; t < 6; ++t) {
        int d = lane + 64 * t;
        float v = we[(size_t)id * DMODEL + d] + pe[(size_t)l * DMODEL + d] + te[d];
        vals[t] = v; s += v;
    }
    s = wave_reduce_sum(s);
    float m = s * (1.0f / DMODEL);
    float s2 = 0.f;
    #pragma unroll
    for (int t = 0; t < 6; ++t) { float dd = vals[t] - m; s2 += dd * dd; }
    s2 = wave_reduce_sum(s2);
    float rs = rsqrtf(s2 * (1.0f / DMODEL) + 1e-12f);
    #pragma unroll
    for (int t = 0; t < 6; ++t) {
        int d = lane + 64 * t;
        float val = (vals[t] - m) * rs * g[d] + bb[d];
        x[(size_t)row * DMODEL + d] = val;
        xb[(size_t)row * DMODEL + d] = f2bf(val);
    }
}

// ---------------------------------------------------------------- residual add + LN (separate residual buffer r)
__global__ __launch_bounds__(256)
void add_ln_kernel(float* x, ushort* __restrict__ xb, const ushort* __restrict__ r,
                   const float* __restrict__ g, const float* __restrict__ bb)
{
    int row = blockIdx.x * 4 + (threadIdx.x >> 6);
    int lane = threadIdx.x & 63;
    float vals[6];
    float s = 0.f;
    #pragma unroll
    for (int t = 0; t < 6; ++t) {
        int d = lane + 64 * t;
        size_t idx = (size_t)row * DMODEL + d;
        float v = x[idx] + bf2f(r[idx]);
        vals[t] = v; s += v;
    }
    s = wave_reduce_sum(s);
    float m = s * (1.0f / DMODEL);
    float s2 = 0.f;
    #pragma unroll
    for (int t = 0; t < 6; ++t) { float dd = vals[t] - m; s2 += dd * dd; }
    s2 = wave_reduce_sum(s2);
    float rs = rsqrtf(s2 * (1.0f / DMODEL) + 1e-12f);
    #pragma unroll
    for (int t = 0; t < 6; ++t) {
        int d = lane + 64 * t;
        size_t idx = (size_t)row * DMODEL + d;
        float val = (vals[t] - m) * rs * g[d] + bb[d];
        x[idx] = val;
        xb[idx] = f2bf(val);
    }
}

// ---------------------------------------------------------------- residual add + LN, residual IN xb (read+rewrite in place)
__global__ __launch_bounds__(256)
void add_ln_ip_kernel(float* x, ushort* xb,
                      const float* __restrict__ g, const float* __restrict__ bb)
{
    int row = blockIdx.x * 4 + (threadIdx.x >> 6);
    int lane = threadIdx.x & 63;
    float vals[6];
    float s = 0.f;
    #pragma unroll
    for (int t = 0; t < 6; ++t) {
        int d = lane + 64 * t;
        size_t idx = (size_t)row * DMODEL + d;
        float v = x[idx] + bf2f(xb[idx]);
        vals[t] = v; s += v;
    }
    s = wave_reduce_sum(s);
    float m = s * (1.0f / DMODEL);
    float s2 = 0.f;
    #pragma unroll
    for (int t = 0; t < 6; ++t) { float dd = vals[t] - m; s2 += dd * dd; }
    s2 = wave_reduce_sum(s2);
    float rs = rsqrtf(s2 * (1.0f / DMODEL) + 1e-12f);
    #pragma unroll
    for (int t = 0; t < 6; ++t) {
        int d = lane + 64 * t;
        size_t idx = (size_t)row * DMODEL + d;
        float val = (vals[t] - m) * rs * g[d] + bb[d];
        x[idx] = val;
        xb[idx] = f2bf(val);
    }
}

// ---------------------------------------------------------------- bf16 MFMA GEMM, async-staged  [verified R7]
// A row stride Astride may differ from K. R12: XCD-chunked A-major block
// swizzle -- work w is ordered row-tile-major (all col-tiles of a row-tile
// consecutive), and each XCD gets a contiguous chunk, so one XCD's working
// set (~32 row-tiles of A + full B panel) stays L2-resident across the
// col-tile re-reads of A. Identity fallback when nwg % 8 != 0.
template<typename TC>
__global__ __launch_bounds__(256)
void gemm_mfma(const ushort* __restrict__ A, const ushort* __restrict__ WT,
               const float* __restrict__ bias, TC* __restrict__ C,
               int M, int N, int K, int Astride, int act)
{
    __shared__ __align__(16) ushort As[128 * 64];   // 16 KB
    __shared__ __align__(16) ushort Bs[128 * 64];   // 16 KB
    int tid = threadIdx.x;
    int lane = tid & 63, wv = tid >> 6;
    int waveM = wv >> 1, waveN = wv & 1;
    int lm = lane & 15, quad = lane >> 4;

    // XCD-aware block swizzle (bijective; nwg % 8 == 0 for all our grids)
    int bid = blockIdx.x + gridDim.x * blockIdx.y;
    int nwg = gridDim.x * gridDim.y;
    int w = bid;
    if ((nwg & 7) == 0) {
        int cpx = nwg >> 3;
        w = (bid & 7) * cpx + (bid >> 3);
    }
    int xt = w / gridDim.y;      // row-tile (A-major ordering)
    int yt = w % gridDim.y;      // col-tile
    int row0 = xt * 128, col0 = yt * 128;

    int srow = lane >> 3, sseg = lane & 7;          // staging: 8 rows x 8 segs

    f32x4 acc[4][4] = {};

    for (int k0 = 0; k0 < K; k0 += 64) {
        __syncthreads();
        #pragma unroll
        for (int i = 0; i < 4; ++i) {
            int r = wv * 32 + i * 8 + srow;
            int sg = sseg ^ (r & 7);
            async16(A  + (size_t)(row0 + r) * Astride + k0 + sg * 8, &As[(wv * 32 + i * 8) * 64]);
            async16(WT + (size_t)(col0 + r) * K + k0 + sg * 8, &Bs[(wv * 32 + i * 8) * 64]);
        }
        __syncthreads();

        #pragma unroll
        for (int ks = 0; ks < 2; ++ks) {
            int physA = ((ks * 4 + quad) ^ (lm & 7)) * 8;
            bf16x8 af[4], bf[4];
            #pragma unroll
            for (int mt = 0; mt < 4; ++mt)
                af[mt] = *(const bf16x8*)&As[(waveM * 64 + mt * 16 + lm) * 64 + physA];
            #pragma unroll
            for (int nt = 0; nt < 4; ++nt)
                bf[nt] = *(const bf16x8*)&Bs[(waveN * 64 + nt * 16 + lm) * 64 + physA];
            #pragma unroll
            for (int mt = 0; mt < 4; ++mt)
                #pragma unroll
                for (int nt = 0; nt < 4; ++nt)
                    acc[mt][nt] = __builtin_amdgcn_mfma_f32_16x16x32_bf16(af[mt], bf[nt], acc[mt][nt], 0, 0, 0);
        }
    }

    #pragma unroll
    for (int mt = 0; mt < 4; ++mt) {
        #pragma unroll
        for (int nt = 0; nt < 4; ++nt) {
            int col = col0 + waveN * 64 + nt * 16 + lm;
            float bv = bias[col];
            #pragma unroll
            for (int r = 0; r < 4; ++r) {
                int row = row0 + waveM * 64 + mt * 16 + quad * 4 + r;
                float val = acc[mt][nt][r] + bv;
                if (act == 1) val = gelu_tanh(gelu_tanh(val));
                if constexpr (sizeof(TC) == 2)
                    C[(size_t)row * N + col] = f2bf(val);
                else
                    C[(size_t)row * N + col] = val;
            }
        }
    }
}

// ---------------------------------------------------------------- beta: wave per row, coalesced bf16 x  [verified R7]
__global__ __launch_bounds__(256)
void beta_kernel(const ushort* __restrict__ xb, const float* __restrict__ Wb,
                 const float* __restrict__ mask, float* __restrict__ beta)
{
    int row = blockIdx.x * 4 + (threadIdx.x >> 6);
    int lane = threadIdx.x & 63;
    float xr[6];
    #pragma unroll
    for (int t = 0; t < 6; ++t) xr[t] = bf2f(xb[(size_t)row * DMODEL + lane + 64 * t]);
    float mine = 0.f;
    #pragma unroll
    for (int h = 0; h < NH; ++h) {
        float p = 0.f;
        #pragma unroll
        for (int t = 0; t < 6; ++t) p += xr[t] * Wb[(size_t)(lane + 64 * t) * NH + h];
        p = wave_reduce_sum(p);
        if (lane == h) mine = p;
    }
    if (lane < NH) beta[(size_t)row * NH + lane] = sigmoidf(mine) * mask[row];
}

// ---------------------------------------------------------------- delta-rule scan v7 [BEST MEASURED: 216 us, R4/R10/R11]
// Wave serves 2 (b,h): half = lane>>5 picks bh, n = lane&31 = state column.
// Lane owns the FULL 32-deep k state for column n (float2-packed). All math
// in-lane. Staging: lane stages full row t0+n with fused q/k l2norm + k*mask.
// Next tile prefetched to regs (vmcnt only). Conflict-free LDS reads.
// o writes into the q-section of qkv (rows < t0+32; prefetch reads >= t0+32).
// Ledger: v6 208, v7 216, v8 230, v9 260, v10 ~324/layer -- v7 is the local
// optimum; parallelism elasticity measured ~1.33x at 4x occupancy.
#define SCAN_T 32
#define SPAD 36
__global__ __launch_bounds__(64)
void scan_kernel(const ushort* __restrict__ qkv, const float* __restrict__ beta,
                 const float* __restrict__ mask,
                 const float* __restrict__ dfast, const float* __restrict__ dslow,
                 ushort* __restrict__ o)
{
    __shared__ __align__(16) float qs[2][SCAN_T][SPAD];
    __shared__ __align__(16) float ks[2][SCAN_T][SPAD];
    __shared__ __align__(16) float vs[2][SCAN_T][SPAD];
    __shared__ float bs[2][SCAN_T];

    int gw = blockIdx.x;
    int lane = threadIdx.x;
    int half = lane >> 5, n = lane & 31;
    int bh = gw * 2 + half;
    int myb = bh / NH, myh = bh % NH;

    float gf = sigmoidf(dfast[myh]);
    float gsl = sigmoidf(dslow[myh]);
    float2 gf2 = make_float2(gf, gf), gs2 = make_float2(gsl, gsl);
    float2 Sf[16], Ss[16];
    #pragma unroll
    for (int j = 0; j < 16; ++j) { Sf[j] = make_float2(0.f, 0.f); Ss[j] = make_float2(0.f, 0.f); }

    // prefetch registers: tile t0=0, lane stages full row t0+n of its bh
    uint4 pq[4], pk[4], pv[4];
    float pb, pmk;
    {
        size_t ra = (size_t)(myb * SEQ + n) * DQKV + myh * DHEAD;
        #pragma unroll
        for (int s = 0; s < 4; ++s) {
            pq[s] = *(const uint4*)(qkv + ra + s * 8);
            pk[s] = *(const uint4*)(qkv + ra + DMODEL + s * 8);
            pv[s] = *(const uint4*)(qkv + ra + 2 * DMODEL + s * 8);
        }
        pb  = beta[(size_t)(myb * SEQ + n) * NH + myh];
        pmk = mask[myb * SEQ + n];
    }

    for (int t0 = 0; t0 < SEQ; t0 += SCAN_T) {
        __syncthreads();
        // ---- stage prefetched tile into LDS, fusing q/k l2norm + k*mask (in-lane)
        {
            ushort tq[32], tk[32], tv[32];
            #pragma unroll
            for (int s = 0; s < 4; ++s) {
                *(uint4*)(tq + s * 8) = pq[s];
                *(uint4*)(tk + s * 8) = pk[s];
                *(uint4*)(tv + s * 8) = pv[s];
            }
            float qv[32], kv[32];
            float sq = 0.f, sk = 0.f;
            #pragma unroll
            for (int j = 0; j < 32; ++j) {
                qv[j] = bf2f(tq[j]); sq += qv[j] * qv[j];
                kv[j] = bf2f(tk[j]); sk += kv[j] * kv[j];
            }
            float rq = 1.0f / (sqrtf(sq) + 1e-6f);
            float rk = pmk / (sqrtf(sk) + 1e-6f);
            #pragma unroll
            for (int s = 0; s < 8; ++s) {
                float4 fq, fk, fv;
                fq.x = qv[s*4+0]*rq; fq.y = qv[s*4+1]*rq; fq.z = qv[s*4+2]*rq; fq.w = qv[s*4+3]*rq;
                fk.x = kv[s*4+0]*rk; fk.y = kv[s*4+1]*rk; fk.z = kv[s*4+2]*rk; fk.w = kv[s*4+3]*rk;
                fv.x = bf2f(tv[s*4+0]); fv.y = bf2f(tv[s*4+1]); fv.z = bf2f(tv[s*4+2]); fv.w = bf2f(tv[s*4+3]);
                *(float4*)&qs[half][n][s * 4] = fq;
                *(float4*)&ks[half][n][s * 4] = fk;
                *(float4*)&vs[half][n][s * 4] = fv;
            }
            bs[half][n] = pb;
        }
        __syncthreads();

        // ---- prefetch next tile (global loads: vmcnt only, hides under compute)
        if (t0 + SCAN_T < SEQ) {
            size_t ra = (size_t)(myb * SEQ + t0 + SCAN_T + n) * DQKV + myh * DHEAD;
            #pragma unroll
            for (int s = 0; s < 4; ++s) {
                pq[s] = *(const uint4*)(qkv + ra + s * 8);
                pk[s] = *(const uint4*)(qkv + ra + DMODEL + s * 8);
                pv[s] = *(const uint4*)(qkv + ra + 2 * DMODEL + s * 8);
            }
            pb  = beta[(size_t)(myb * SEQ + t0 + SCAN_T + n) * NH + myh];
            pmk = mask[myb * SEQ + t0 + SCAN_T + n];
        }

        #pragma unroll 4
        for (int t = 0; t < SCAN_T; ++t) {
            float2 kt[16], qt[16];
            #pragma unroll
            for (int s = 0; s < 8; ++s) {
                *(float4*)&kt[s * 2] = *(const float4*)&ks[half][t][s * 4];
                *(float4*)&qt[s * 2] = *(const float4*)&qs[half][t][s * 4];
            }
            float vt = vs[half][t][n], bt = bs[half][t];

            float2 pf0 = kt[0] * Sf[0], pf1 = kt[1] * Sf[1], pf2 = kt[2] * Sf[2], pf3 = kt[3] * Sf[3];
            float2 ps0 = kt[0] * Ss[0], ps1 = kt[1] * Ss[1], ps2 = kt[2] * Ss[2], ps3 = kt[3] * Ss[3];
            #pragma unroll
            for (int j = 4; j < 16; j += 4) {
                pf0 += kt[j] * Sf[j];     pf1 += kt[j + 1] * Sf[j + 1];
                pf2 += kt[j + 2] * Sf[j + 2]; pf3 += kt[j + 3] * Sf[j + 3];
                ps0 += kt[j] * Ss[j];     ps1 += kt[j + 1] * Ss[j + 1];
                ps2 += kt[j + 2] * Ss[j + 2]; ps3 += kt[j + 3] * Ss[j + 3];
            }
            float2 pfv = (pf0 + pf1) + (pf2 + pf3);
            float2 psv = (ps0 + ps1) + (ps2 + ps3);
            float pft = pfv.x + pfv.y, pst = psv.x + psv.y;

            float cf = bt * (vt - pft), cs = bt * (vt - pst);
            float2 cf2 = make_float2(cf, cf), cs2 = make_float2(cs, cs);

            float2 o0 = make_float2(0.f, 0.f), o1 = o0, o2 = o0, o3 = o0;
            #pragma unroll
            for (int j = 0; j < 16; j += 4) {
                Sf[j] = gf2 * Sf[j] + kt[j] * cf2;         Ss[j] = gs2 * Ss[j] + kt[j] * cs2;
                Sf[j+1] = gf2 * Sf[j+1] + kt[j+1] * cf2;   Ss[j+1] = gs2 * Ss[j+1] + kt[j+1] * cs2;
                Sf[j+2] = gf2 * Sf[j+2] + kt[j+2] * cf2;   Ss[j+2] = gs2 * Ss[j+2] + kt[j+2] * cs2;
                Sf[j+3] = gf2 * Sf[j+3] + kt[j+3] * cf2;   Ss[j+3] = gs2 * Ss[j+3] + kt[j+3] * cs2;
                o0 += qt[j] * (Sf[j] + Ss[j]);
                o1 += qt[j+1] * (Sf[j+1] + Ss[j+1]);
                o2 += qt[j+2] * (Sf[j+2] + Ss[j+2]);
                o3 += qt[j+3] * (Sf[j+3] + Ss[j+3]);
            }
            float2 ov = (o0 + o1) + (o2 + o3);
            float ott = ov.x + ov.y;
            // o into q-section of qkv: row stride DQKV (both halves write their own bh)
            o[((size_t)(myb * SEQ + t0 + t)) * DQKV + myh * DHEAD + n] = f2bf(0.5f * ott);
        }
    }
}

// ---------------------------------------------------------------- masked mean-pool + l2 normalize
__global__ __launch_bounds__(384)
void pool_kernel(const float* __restrict__ x, const float* __restrict__ mask,
                 float* __restrict__ out)
{
    int b = blockIdx.x;
    int d = threadIdx.x;
    float acc = 0.f, msum = 0.f;
    for (int l = 0; l < SEQ; ++l) {
        float mk = mask[b * SEQ + l];
        acc += x[((size_t)b * SEQ + l) * DMODEL + d] * mk;
        msum += mk;
    }
    float emb = acc / fmaxf(msum, 1e-9f);
    __shared__ float red[6];
    float ss = wave_reduce_sum(emb * emb);
    int wvi = d >> 6, ln = d & 63;
    if (ln == 0) red[wvi] = ss;
    __syncthreads();
    float tot = 0.f;
    #pragma unroll
    for (int i = 0; i < 6; ++i) tot += red[i];
    float nrm = fmaxf(sqrtf(tot), 1e-12f);
    out[(size_t)b * DMODEL + d] = emb / nrm;
}

// ---------------------------------------------------------------- launch

extern "C" void kernel_launch(void* const* d_in, const int* in_sizes, int n_in,
                              void* d_out, int out_size, void* d_ws, size_t ws_size,
                              hipStream_t stream)
{
    const int*   ids   = (const int*)d_in[0];
    const float* mask  = (const float*)d_in[1];
    const float* we    = (const float*)d_in[2];
    const float* pe    = (const float*)d_in[3];
    const float* te    = (const float*)d_in[4];
    const float* elg   = (const float*)d_in[5];
    const float* elb   = (const float*)d_in[6];
    const float* Wq    = (const float*)d_in[7];
    const float* bq    = (const float*)d_in[8];
    const float* Wk    = (const float*)d_in[9];
    const float* bk    = (const float*)d_in[10];
    const float* Wv    = (const float*)d_in[11];
    const float* bv    = (const float*)d_in[12];
    const float* Wb    = (const float*)d_in[13];
    const float* dfast = (const float*)d_in[14];
    const float* dslow = (const float*)d_in[15];
    const float* Wo    = (const float*)d_in[16];
    const float* bo    = (const float*)d_in[17];
    const float* l1g   = (const float*)d_in[18];
    const float* l1b   = (const float*)d_in[19];
    const float* W1    = (const float*)d_in[20];
    const float* b1    = (const float*)d_in[21];
    const float* W2    = (const float*)d_in[22];
    const float* b2    = (const float*)d_in[23];
    const float* l2g   = (const float*)d_in[24];
    const float* l2b   = (const float*)d_in[25];
    float* out = (float*)d_out;

    // ---- workspace: 199.0 MB total (proven ceiling 202.9 MB, R4) ----
    const size_t RD = (size_t)NROWS * DMODEL;    // 12,582,912 elements
    float* x      = (float*)d_ws;                      // 50.33 MB
    float* betab  = x + RD;                            //  1.57 MB
    ushort* xb    = (ushort*)(betab + (size_t)NROWS * NH);   // 25.17 MB
    ushort* qkvb  = xb + RD;                           // 75.50 MB  [row][1152]
    ushort* ab    = qkvb + (size_t)NROWS * DQKV;       // 25.17 MB (attn out; FFN: tail of h)
    ushort* WqkvT = ab + RD;                           //  5.31 MB [L][1152][384]
    ushort* WoT   = WqkvT + (size_t)NLAYER * DQKV * DMODEL;  // 1.77 MB
    ushort* W1T   = WoT + (size_t)NLAYER * DMODEL * DMODEL;  // 7.08 MB [L][1536][384]
    ushort* W2T   = W1T + (size_t)NLAYER * DMODEL * DFFN;    // 7.08 MB [L][384][1536]
    float* biasqkv = (float*)(W2T + (size_t)NLAYER * DFFN * DMODEL); // 27 KB

    dim3 blk256(256);
    dim3 rowsGrid(NROWS / 4);
    dim3 gemmGrid_QKV(NROWS / 128, DQKV / 128);      // (256, 9)
    dim3 gemmGrid_D(NROWS / 128, DMODEL / 128);      // (256, 3)
    dim3 gemmGrid_F1(NROWS / 128, DFFN / 128);       // (256, 12) unchunked
    dim3 gemmGrid_F2(NROWS / 128, DMODEL / 128);     // (256, 3)  unchunked
    dim3 scanGrid(BATCH * NH / 2);                   // 384 single-wave blocks, 2 bh each

    const size_t lsQKV = (size_t)DQKV * DMODEL;
    convT_kernel<<<dim3(12, 12, NLAYER), blk256, 0, stream>>>(Wq, WqkvT, DMODEL, DMODEL, lsQKV, 0);
    convT_kernel<<<dim3(12, 12, NLAYER), blk256, 0, stream>>>(Wk, WqkvT, DMODEL, DMODEL, lsQKV, DMODEL);
    convT_kernel<<<dim3(12, 12, NLAYER), blk256, 0, stream>>>(Wv, WqkvT, DMODEL, DMODEL, lsQKV, 2*DMODEL);
    convT_kernel<<<dim3(12, 12, NLAYER), blk256, 0, stream>>>(Wo, WoT, DMODEL, DMODEL, (size_t)DMODEL*DMODEL, 0);
    convT_kernel<<<dim3(12, 48, NLAYER), blk256, 0, stream>>>(W1, W1T, DMODEL, DFFN, (size_t)DMODEL*DFFN, 0);
    convT_kernel<<<dim3(48, 12, NLAYER), blk256, 0, stream>>>(W2, W2T, DFFN, DMODEL, (size_t)DFFN*DMODEL, 0);
    biascat_kernel<<<dim3(NLAYER), dim3(384), 0, stream>>>(bq, bk, bv, biasqkv);

    embed_ln_kernel<<<rowsGrid, blk256, 0, stream>>>(ids, we, pe, te, elg, elb, x, xb);

    for (int i = 0; i < NLAYER; ++i) {
        const ushort* WqkvT_i = WqkvT + (size_t)i * lsQKV;
        const ushort* WoT_i   = WoT + (size_t)i * DMODEL * DMODEL;
        const float*  Wb_i    = Wb  + (size_t)i * DMODEL * NH;
        const ushort* W1T_i   = W1T + (size_t)i * DMODEL * DFFN;
        const ushort* W2T_i   = W2T + (size_t)i * DFFN * DMODEL;

        gemm_mfma<ushort><<<gemmGrid_QKV, blk256, 0, stream>>>(xb, WqkvT_i, biasqkv + (size_t)i * DQKV,
                                                               qkvb, NROWS, DQKV, DMODEL, DMODEL, 0);
        beta_kernel<<<rowsGrid, blk256, 0, stream>>>(xb, Wb_i, mask, betab);
        // q/k l2norm + k*mask fused into scan staging; o overwrites q-section of qkvb
        scan_kernel<<<scanGrid, dim3(64), 0, stream>>>(qkvb, betab, mask,
                                                       dfast + i * NH, dslow + i * NH, qkvb);
        // Wo GEMM reads strided o (Astride = DQKV)
        gemm_mfma<ushort><<<gemmGrid_D, blk256, 0, stream>>>(qkvb, WoT_i, bo + i * DMODEL, ab,
                                                             NROWS, DMODEL, DMODEL, DQKV, 0);
        add_ln_kernel<<<rowsGrid, blk256, 0, stream>>>(x, xb, ab, l1g + i * DMODEL, l1b + i * DMODEL);

        // FFN UNCHUNKED (R11 win): h spans qkvb+ab (contiguous, exactly
        // 100,663,296 B; both dead). W2-out -> xb (dead after W1 GEMM);
        // add_ln_ip reads residual from xb and rewrites it.
        {
            ushort* hbuf = qkvb;   // 100.66 MB window (qkvb..ab end)
            gemm_mfma<ushort><<<gemmGrid_F1, blk256, 0, stream>>>(xb, W1T_i, b1 + i * DFFN, hbuf,
                                                                  NROWS, DFFN, DMODEL, DMODEL, 1);
            gemm_mfma<ushort><<<gemmGrid_F2, blk256, 0, stream>>>(hbuf, W2T_i, b2 + i * DMODEL, xb,
                                                                  NROWS, DMODEL, DFFN, DFFN, 0);
            add_ln_ip_kernel<<<rowsGrid, blk256, 0, stream>>>(x, xb, l2g + i * DMODEL, l2b + i * DMODEL);
        }
    }

    pool_kernel<<<dim3(BATCH), dim3(384), 0, stream>>>(x, mask, out);
}

// Round 13
// 2797.355 us; speedup vs baseline: 1.4485x; 1.0786x over previous
//
#include <hip/hip_runtime.h>
#include <cstdint>
#include <cstddef>
#include <cmath>

#define NLAYER 6
#define NH 12
#define DMODEL 384
#define DHEAD 32
#define DFFN 1536
#define BATCH 64
#define SEQ 512
#define NROWS (BATCH*SEQ)   // 32768
#define DQKV 1152           // fused q|k|v row length

typedef unsigned short ushort;
typedef __attribute__((ext_vector_type(8))) short bf16x8;   // 8 bf16 = 4 VGPRs
typedef __attribute__((ext_vector_type(4))) float f32x4;

// ---------------------------------------------------------------- utilities

__device__ inline float bf2f(ushort u) {
    union { unsigned int i; float f; } c; c.i = ((unsigned int)u) << 16; return c.f;
}
__device__ inline ushort f2bf(float f) {
    union { float f; unsigned int i; } c; c.f = f;
    unsigned int i = c.i;
    unsigned int lsb = (i >> 16) & 1u;
    i += 0x7fffu + lsb;          // round-to-nearest-even
    return (ushort)(i >> 16);
}

__device__ inline float wave_reduce_sum(float v) {
    #pragma unroll
    for (int m = 32; m >= 1; m >>= 1) v += __shfl_xor(v, m, 64);
    return v;
}

__device__ inline float sigmoidf(float x) { return 1.0f / (1.0f + expf(-x)); }

// fast exp-based tanh-gelu (R12 win): tanh(y) = 1 - 2/(e^{2y}+1); ~8 VALU ops.
__device__ inline float gelu_tanh(float x) {
    const float c = 0.7978845608028654f; // sqrt(2/pi)
    float y = c * (x + 0.044715f * x * x * x);
    float e = __expf(2.0f * y);
    float t = 1.0f - 2.0f * __builtin_amdgcn_rcpf(e + 1.0f);
    return 0.5f * x * (1.0f + t);
}

// async global->LDS, 16 bytes per lane; lds base must be wave-uniform
__device__ inline void async16(const ushort* g, ushort* l) {
    __builtin_amdgcn_global_load_lds(
        (const __attribute__((address_space(1))) unsigned int*)g,
        (__attribute__((address_space(3))) unsigned int*)l,
        16, 0, 0);
}

// dot of two float2[16] register arrays -> scalar (4 chains + tree)
__device__ inline float dot16(const float2* a, const float2* b) {
    float2 s0 = a[0]*b[0], s1 = a[1]*b[1], s2 = a[2]*b[2], s3 = a[3]*b[3];
    #pragma unroll
    for (int j = 4; j < 16; j += 4) {
        s0 += a[j]*b[j]; s1 += a[j+1]*b[j+1]; s2 += a[j+2]*b[j+2]; s3 += a[j+3]*b[j+3];
    }
    float2 s = (s0 + s1) + (s2 + s3);
    return s.x + s.y;
}

// ---------------------------------------------------------------- weight convert+transpose
__global__ __launch_bounds__(256)
void convT_kernel(const float* __restrict__ W, ushort* __restrict__ WT, int K, int N,
                  size_t lStride, int nOff)
{
    __shared__ float t[32][33];
    int k0 = blockIdx.x * 32, n0 = blockIdx.y * 32, L = blockIdx.z;
    const float* Wl = W + (size_t)L * K * N;
    ushort* WTl = WT + (size_t)L * lStride;
    int tx = threadIdx.x & 31, ty = threadIdx.x >> 5;   // 32 x 8
    #pragma unroll
    for (int i = 0; i < 4; ++i)
        t[ty + 8 * i][tx] = Wl[(size_t)(k0 + ty + 8 * i) * N + n0 + tx];
    __syncthreads();
    #pragma unroll
    for (int i = 0; i < 4; ++i)
        WTl[(size_t)(nOff + n0 + ty + 8 * i) * K + k0 + tx] = f2bf(t[tx][ty + 8 * i]);
}

// ---------------------------------------------------------------- fused qkv bias concat: [L][1152]
__global__ __launch_bounds__(384)
void biascat_kernel(const float* __restrict__ bq, const float* __restrict__ bk,
                    const float* __restrict__ bv, float* __restrict__ dst)
{
    int L = blockIdx.x, d = threadIdx.x;
    dst[(size_t)L * DQKV + d]             = bq[(size_t)L * DMODEL + d];
    dst[(size_t)L * DQKV + DMODEL + d]    = bk[(size_t)L * DMODEL + d];
    dst[(size_t)L * DQKV + 2*DMODEL + d]  = bv[(size_t)L * DMODEL + d];
}

// ---------------------------------------------------------------- embedding + LN (writes fp32 x and bf16 xb)
__global__ __launch_bounds__(256)
void embed_ln_kernel(const int* __restrict__ ids, const float* __restrict__ we,
                     const float* __restrict__ pe, const float* __restrict__ te,
                     const float* __restrict__ g, const float* __restrict__ bb,
                     float* __restrict__ x, ushort* __restrict__ xb)
{
    int row = blockIdx.x * 4 + (threadIdx.x >> 6);
    int lane = threadIdx.x & 63;
    int l = row & (SEQ - 1);
    int id = ids[row];
    float vals[6];
    float s = 0.f;
    #pragma unroll
    for (int t = 0; t < 6; ++t) {
        int d = lane + 64 * t;
        float v = we[(size_t)id * DMODEL + d] + pe[(size_t)l * DMODEL + d] + te[d];
        vals[t] = v; s += v;
    }
    s = wave_reduce_sum(s);
    float m = s * (1.0f / DMODEL);
    float s2 = 0.f;
    #pragma unroll
    for (int t = 0; t < 6; ++t) { float dd = vals[t] - m; s2 += dd * dd; }
    s2 = wave_reduce_sum(s2);
    float rs = rsqrtf(s2 * (1.0f / DMODEL) + 1e-12f);
    #pragma unroll
    for (int t = 0; t < 6; ++t) {
        int d = lane + 64 * t;
        float val = (vals[t] - m) * rs * g[d] + bb[d];
        x[(size_t)row * DMODEL + d] = val;
        xb[(size_t)row * DMODEL + d] = f2bf(val);
    }
}

// ---------------------------------------------------------------- residual add + LN (separate residual buffer r)
__global__ __launch_bounds__(256)
void add_ln_kernel(float* x, ushort* __restrict__ xb, const ushort* __restrict__ r,
                   const float* __restrict__ g, const float* __restrict__ bb)
{
    int row = blockIdx.x * 4 + (threadIdx.x >> 6);
    int lane = threadIdx.x & 63;
    float vals[6];
    float s = 0.f;
    #pragma unroll
    for (int t = 0; t < 6; ++t) {
        int d = lane + 64 * t;
        size_t idx = (size_t)row * DMODEL + d;
        float v = x[idx] + bf2f(r[idx]);
        vals[t] = v; s += v;
    }
    s = wave_reduce_sum(s);
    float m = s * (1.0f / DMODEL);
    float s2 = 0.f;
    #pragma unroll
    for (int t = 0; t < 6; ++t) { float dd = vals[t] - m; s2 += dd * dd; }
    s2 = wave_reduce_sum(s2);
    float rs = rsqrtf(s2 * (1.0f / DMODEL) + 1e-12f);
    #pragma unroll
    for (int t = 0; t < 6; ++t) {
        int d = lane + 64 * t;
        size_t idx = (size_t)row * DMODEL + d;
        float val = (vals[t] - m) * rs * g[d] + bb[d];
        x[idx] = val;
        xb[idx] = f2bf(val);
    }
}

// ---------------------------------------------------------------- residual add + LN, residual IN xb (in place)
__global__ __launch_bounds__(256)
void add_ln_ip_kernel(float* x, ushort* xb,
                      const float* __restrict__ g, const float* __restrict__ bb)
{
    int row = blockIdx.x * 4 + (threadIdx.x >> 6);
    int lane = threadIdx.x & 63;
    float vals[6];
    float s = 0.f;
    #pragma unroll
    for (int t = 0; t < 6; ++t) {
        int d = lane + 64 * t;
        size_t idx = (size_t)row * DMODEL + d;
        float v = x[idx] + bf2f(xb[idx]);
        vals[t] = v; s += v;
    }
    s = wave_reduce_sum(s);
    float m = s * (1.0f / DMODEL);
    float s2 = 0.f;
    #pragma unroll
    for (int t = 0; t < 6; ++t) { float dd = vals[t] - m; s2 += dd * dd; }
    s2 = wave_reduce_sum(s2);
    float rs = rsqrtf(s2 * (1.0f / DMODEL) + 1e-12f);
    #pragma unroll
    for (int t = 0; t < 6; ++t) {
        int d = lane + 64 * t;
        size_t idx = (size_t)row * DMODEL + d;
        float val = (vals[t] - m) * rs * g[d] + bb[d];
        x[idx] = val;
        xb[idx] = f2bf(val);
    }
}

// ---------------------------------------------------------------- bf16 MFMA GEMM, async-staged [verified R7]
// R12 win: XCD-chunked A-major block swizzle (identity fallback nwg%8!=0).
template<typename TC>
__global__ __launch_bounds__(256)
void gemm_mfma(const ushort* __restrict__ A, const ushort* __restrict__ WT,
               const float* __restrict__ bias, TC* __restrict__ C,
               int M, int N, int K, int Astride, int act)
{
    __shared__ __align__(16) ushort As[128 * 64];   // 16 KB
    __shared__ __align__(16) ushort Bs[128 * 64];   // 16 KB
    int tid = threadIdx.x;
    int lane = tid & 63, wv = tid >> 6;
    int waveM = wv >> 1, waveN = wv & 1;
    int lm = lane & 15, quad = lane >> 4;

    int bid = blockIdx.x + gridDim.x * blockIdx.y;
    int nwg = gridDim.x * gridDim.y;
    int w = bid;
    if ((nwg & 7) == 0) {
        int cpx = nwg >> 3;
        w = (bid & 7) * cpx + (bid >> 3);
    }
    int xt = w / gridDim.y;      // row-tile (A-major ordering)
    int yt = w % gridDim.y;      // col-tile
    int row0 = xt * 128, col0 = yt * 128;

    int srow = lane >> 3, sseg = lane & 7;          // staging: 8 rows x 8 segs

    f32x4 acc[4][4] = {};

    for (int k0 = 0; k0 < K; k0 += 64) {
        __syncthreads();
        #pragma unroll
        for (int i = 0; i < 4; ++i) {
            int r = wv * 32 + i * 8 + srow;
            int sg = sseg ^ (r & 7);
            async16(A  + (size_t)(row0 + r) * Astride + k0 + sg * 8, &As[(wv * 32 + i * 8) * 64]);
            async16(WT + (size_t)(col0 + r) * K + k0 + sg * 8, &Bs[(wv * 32 + i * 8) * 64]);
        }
        __syncthreads();

        #pragma unroll
        for (int ks = 0; ks < 2; ++ks) {
            int physA = ((ks * 4 + quad) ^ (lm & 7)) * 8;
            bf16x8 af[4], bf[4];
            #pragma unroll
            for (int mt = 0; mt < 4; ++mt)
                af[mt] = *(const bf16x8*)&As[(waveM * 64 + mt * 16 + lm) * 64 + physA];
            #pragma unroll
            for (int nt = 0; nt < 4; ++nt)
                bf[nt] = *(const bf16x8*)&Bs[(waveN * 64 + nt * 16 + lm) * 64 + physA];
            #pragma unroll
            for (int mt = 0; mt < 4; ++mt)
                #pragma unroll
                for (int nt = 0; nt < 4; ++nt)
                    acc[mt][nt] = __builtin_amdgcn_mfma_f32_16x16x32_bf16(af[mt], bf[nt], acc[mt][nt], 0, 0, 0);
        }
    }

    #pragma unroll
    for (int mt = 0; mt < 4; ++mt) {
        #pragma unroll
        for (int nt = 0; nt < 4; ++nt) {
            int col = col0 + waveN * 64 + nt * 16 + lm;
            float bv = bias[col];
            #pragma unroll
            for (int r = 0; r < 4; ++r) {
                int row = row0 + waveM * 64 + mt * 16 + quad * 4 + r;
                float val = acc[mt][nt][r] + bv;
                if (act == 1) val = gelu_tanh(gelu_tanh(val));
                if constexpr (sizeof(TC) == 2)
                    C[(size_t)row * N + col] = f2bf(val);
                else
                    C[(size_t)row * N + col] = val;
            }
        }
    }
}

// ---------------------------------------------------------------- beta: wave per row, coalesced bf16 x  [verified R7]
__global__ __launch_bounds__(256)
void beta_kernel(const ushort* __restrict__ xb, const float* __restrict__ Wb,
                 const float* __restrict__ mask, float* __restrict__ beta)
{
    int row = blockIdx.x * 4 + (threadIdx.x >> 6);
    int lane = threadIdx.x & 63;
    float xr[6];
    #pragma unroll
    for (int t = 0; t < 6; ++t) xr[t] = bf2f(xb[(size_t)row * DMODEL + lane + 64 * t]);
    float mine = 0.f;
    #pragma unroll
    for (int h = 0; h < NH; ++h) {
        float p = 0.f;
        #pragma unroll
        for (int t = 0; t < 6; ++t) p += xr[t] * Wb[(size_t)(lane + 64 * t) * NH + h];
        p = wave_reduce_sum(p);
        if (lane == h) mine = p;
    }
    if (lane < NH) beta[(size_t)row * NH + lane] = sigmoidf(mine) * mask[row];
}

// ---------------------------------------------------------------- delta-rule scan v11: state-split halves
// Ledger model fit (v6 208 / v7 216 / v8 230 / v9 260 / v10 324):
//   T_step ~ N_insts x ~7cyc (lone-wave exposed latency) + N_crit_shfls x ~150cyc.
//   v7: 130x7~910; v6: 65x7+2x150~900 -- effects cancelled, masking the work lever.
// v11 tests the untested cell: HALF the work per lane AND ZERO cross-lane ops
// in the critical chain. One wave per (b,h) (768 blocks, 2x occupancy):
// half 0 owns the full fast state Sf, half 1 the slow state Ss (lane n = state
// column n, 32-deep k as float2[16]). p->c->S chain entirely intra-half.
// Only o needs cross-half combine -- OFF the critical path (o never feeds S):
// exchanged via a 64-wide LDS scratch (same-wave program order, no barrier;
// 2-way bank alias free per m136). Staging: element-split (lane loads 16 elems
// of row n), one-time-per-tile shfl_xor(32) completes the l2 norms.
// Exact same arithmetic as v7 (partitioning only).
#define SCAN_T 32
#define SPAD 36
__global__ __launch_bounds__(64)
void scan_kernel(const ushort* __restrict__ qkv, const float* __restrict__ beta,
                 const float* __restrict__ mask,
                 const float* __restrict__ dfast, const float* __restrict__ dslow,
                 ushort* __restrict__ o)
{
    __shared__ __align__(16) float qs[SCAN_T][SPAD];
    __shared__ __align__(16) float ks[SCAN_T][SPAD];
    __shared__ __align__(16) float vs[SCAN_T][SPAD];
    __shared__ float bs[SCAN_T];
    __shared__ float osb[64];          // per-step o exchange (intra-wave)

    int bh = blockIdx.x;               // 768 blocks, one (b,h) each
    int lane = threadIdx.x;
    int half = lane >> 5, n = lane & 31;
    int h16 = half << 4;
    int myb = bh / NH, myh = bh % NH;

    float g = sigmoidf(half ? dslow[myh] : dfast[myh]);
    float2 g2 = make_float2(g, g);
    float2 S[16];
    #pragma unroll
    for (int j = 0; j < 16; ++j) S[j] = make_float2(0.f, 0.f);

    // prefetch regs: lane (half,n) stages 16 elements (offset h16) of row t0+n
    uint4 pq[2], pk[2], pv[2];
    float pb, pmk;
    {
        size_t ra = (size_t)(myb * SEQ + n) * DQKV + myh * DHEAD + h16;
        pq[0] = *(const uint4*)(qkv + ra);     pq[1] = *(const uint4*)(qkv + ra + 8);
        pk[0] = *(const uint4*)(qkv + ra + DMODEL);     pk[1] = *(const uint4*)(qkv + ra + DMODEL + 8);
        pv[0] = *(const uint4*)(qkv + ra + 2*DMODEL);   pv[1] = *(const uint4*)(qkv + ra + 2*DMODEL + 8);
        pb  = beta[(size_t)(myb * SEQ + n) * NH + myh];
        pmk = mask[myb * SEQ + n];
    }

    for (int t0 = 0; t0 < SEQ; t0 += SCAN_T) {
        __syncthreads();
        // ---- stage tile: fused q/k l2norm (cross-half shfl once) + k*mask
        {
            ushort tq[16], tk[16], tv[16];
            *(uint4*)tq = pq[0]; *(uint4*)(tq + 8) = pq[1];
            *(uint4*)tk = pk[0]; *(uint4*)(tk + 8) = pk[1];
            *(uint4*)tv = pv[0]; *(uint4*)(tv + 8) = pv[1];
            float qv[16], kv[16];
            float sq = 0.f, sk = 0.f;
            #pragma unroll
            for (int j = 0; j < 16; ++j) {
                qv[j] = bf2f(tq[j]); sq += qv[j] * qv[j];
                kv[j] = bf2f(tk[j]); sk += kv[j] * kv[j];
            }
            sq += __shfl_xor(sq, 32, 64);   // partner lane = other half of same row
            sk += __shfl_xor(sk, 32, 64);
            float rq = 1.0f / (sqrtf(sq) + 1e-6f);
            float rk = pmk / (sqrtf(sk) + 1e-6f);
            #pragma unroll
            for (int s2 = 0; s2 < 4; ++s2) {
                float4 fq, fk, fv;
                fq.x = qv[s2*4+0]*rq; fq.y = qv[s2*4+1]*rq; fq.z = qv[s2*4+2]*rq; fq.w = qv[s2*4+3]*rq;
                fk.x = kv[s2*4+0]*rk; fk.y = kv[s2*4+1]*rk; fk.z = kv[s2*4+2]*rk; fk.w = kv[s2*4+3]*rk;
                fv.x = bf2f(tv[s2*4+0]); fv.y = bf2f(tv[s2*4+1]); fv.z = bf2f(tv[s2*4+2]); fv.w = bf2f(tv[s2*4+3]);
                *(float4*)&qs[n][h16 + s2*4] = fq;
                *(float4*)&ks[n][h16 + s2*4] = fk;
                *(float4*)&vs[n][h16 + s2*4] = fv;
            }
            if (!half) bs[n] = pb;
        }
        __syncthreads();

        // ---- prefetch next tile (vmcnt only; rows >= t0+32, o-writes < t0+32)
        if (t0 + SCAN_T < SEQ) {
            size_t ra = (size_t)(myb * SEQ + t0 + SCAN_T + n) * DQKV + myh * DHEAD + h16;
            pq[0] = *(const uint4*)(qkv + ra);     pq[1] = *(const uint4*)(qkv + ra + 8);
            pk[0] = *(const uint4*)(qkv + ra + DMODEL);     pk[1] = *(const uint4*)(qkv + ra + DMODEL + 8);
            pv[0] = *(const uint4*)(qkv + ra + 2*DMODEL);   pv[1] = *(const uint4*)(qkv + ra + 2*DMODEL + 8);
            pb  = beta[(size_t)(myb * SEQ + t0 + SCAN_T + n) * NH + myh];
            pmk = mask[myb * SEQ + t0 + SCAN_T + n];
        }

        #pragma unroll 4
        for (int t = 0; t < SCAN_T; ++t) {
            float2 kt[16], qt[16];
            #pragma unroll
            for (int s2 = 0; s2 < 8; ++s2) {
                *(float4*)&kt[s2 * 2] = *(const float4*)&ks[t][s2 * 4];   // full row: broadcast
                *(float4*)&qt[s2 * 2] = *(const float4*)&qs[t][s2 * 4];
            }
            float vt = vs[t][n], bt = bs[t];

            float p = dot16(kt, S);
            float c = bt * (vt - p);
            float2 c2 = make_float2(c, c);

            float2 o0 = make_float2(0.f, 0.f), o1 = o0, o2 = o0, o3 = o0;
            #pragma unroll
            for (int j = 0; j < 16; j += 4) {
                S[j]   = g2 * S[j]   + kt[j]   * c2;
                S[j+1] = g2 * S[j+1] + kt[j+1] * c2;
                S[j+2] = g2 * S[j+2] + kt[j+2] * c2;
                S[j+3] = g2 * S[j+3] + kt[j+3] * c2;
                o0 += qt[j]   * S[j];
                o1 += qt[j+1] * S[j+1];
                o2 += qt[j+2] * S[j+2];
                o3 += qt[j+3] * S[j+3];
            }
            float2 ov = (o0 + o1) + (o2 + o3);
            float oh = ov.x + ov.y;

            // cross-half combine via LDS (same wave, program order; no barrier)
            osb[lane] = oh;
            float osum = osb[n] + osb[n + 32];
            if (lane < 32)
                o[((size_t)(myb * SEQ + t0 + t)) * DQKV + myh * DHEAD + n] = f2bf(0.5f * osum);
        }
    }
}

// ---------------------------------------------------------------- masked mean-pool + l2 normalize
__global__ __launch_bounds__(384)
void pool_kernel(const float* __restrict__ x, const float* __restrict__ mask,
                 float* __restrict__ out)
{
    int b = blockIdx.x;
    int d = threadIdx.x;
    float acc = 0.f, msum = 0.f;
    for (int l = 0; l < SEQ; ++l) {
        float mk = mask[b * SEQ + l];
        acc += x[((size_t)b * SEQ + l) * DMODEL + d] * mk;
        msum += mk;
    }
    float emb = acc / fmaxf(msum, 1e-9f);
    __shared__ float red[6];
    float ss = wave_reduce_sum(emb * emb);
    int wvi = d >> 6, ln = d & 63;
    if (ln == 0) red[wvi] = ss;
    __syncthreads();
    float tot = 0.f;
    #pragma unroll
    for (int i = 0; i < 6; ++i) tot += red[i];
    float nrm = fmaxf(sqrtf(tot), 1e-12f);
    out[(size_t)b * DMODEL + d] = emb / nrm;
}

// ---------------------------------------------------------------- launch

extern "C" void kernel_launch(void* const* d_in, const int* in_sizes, int n_in,
                              void* d_out, int out_size, void* d_ws, size_t ws_size,
                              hipStream_t stream)
{
    const int*   ids   = (const int*)d_in[0];
    const float* mask  = (const float*)d_in[1];
    const float* we    = (const float*)d_in[2];
    const float* pe    = (const float*)d_in[3];
    const float* te    = (const float*)d_in[4];
    const float* elg   = (const float*)d_in[5];
    const float* elb   = (const float*)d_in[6];
    const float* Wq    = (const float*)d_in[7];
    const float* bq    = (const float*)d_in[8];
    const float* Wk    = (const float*)d_in[9];
    const float* bk    = (const float*)d_in[10];
    const float* Wv    = (const float*)d_in[11];
    const float* bv    = (const float*)d_in[12];
    const float* Wb    = (const float*)d_in[13];
    const float* dfast = (const float*)d_in[14];
    const float* dslow = (const float*)d_in[15];
    const float* Wo    = (const float*)d_in[16];
    const float* bo    = (const float*)d_in[17];
    const float* l1g   = (const float*)d_in[18];
    const float* l1b   = (const float*)d_in[19];
    const float* W1    = (const float*)d_in[20];
    const float* b1    = (const float*)d_in[21];
    const float* W2    = (const float*)d_in[22];
    const float* b2    = (const float*)d_in[23];
    const float* l2g   = (const float*)d_in[24];
    const float* l2b   = (const float*)d_in[25];
    float* out = (float*)d_out;

    // ---- workspace: 199.0 MB total (proven ceiling 202.9 MB, R4) ----
    const size_t RD = (size_t)NROWS * DMODEL;    // 12,582,912 elements
    float* x      = (float*)d_ws;                      // 50.33 MB
    float* betab  = x + RD;                            //  1.57 MB
    ushort* xb    = (ushort*)(betab + (size_t)NROWS * NH);   // 25.17 MB
    ushort* qkvb  = xb + RD;                           // 75.50 MB  [row][1152]
    ushort* ab    = qkvb + (size_t)NROWS * DQKV;       // 25.17 MB (attn out; FFN: tail of h)
    ushort* WqkvT = ab + RD;                           //  5.31 MB [L][1152][384]
    ushort* WoT   = WqkvT + (size_t)NLAYER * DQKV * DMODEL;  // 1.77 MB
    ushort* W1T   = WoT + (size_t)NLAYER * DMODEL * DMODEL;  // 7.08 MB [L][1536][384]
    ushort* W2T   = W1T + (size_t)NLAYER * DMODEL * DFFN;    // 7.08 MB [L][384][1536]
    float* biasqkv = (float*)(W2T + (size_t)NLAYER * DFFN * DMODEL); // 27 KB

    dim3 blk256(256);
    dim3 rowsGrid(NROWS / 4);
    dim3 gemmGrid_QKV(NROWS / 128, DQKV / 128);      // (256, 9)
    dim3 gemmGrid_D(NROWS / 128, DMODEL / 128);      // (256, 3)
    dim3 gemmGrid_F1(NROWS / 128, DFFN / 128);       // (256, 12) unchunked
    dim3 gemmGrid_F2(NROWS / 128, DMODEL / 128);     // (256, 3)  unchunked
    dim3 scanGrid(BATCH * NH);                       // 768 single-wave blocks (state-split)

    const size_t lsQKV = (size_t)DQKV * DMODEL;
    convT_kernel<<<dim3(12, 12, NLAYER), blk256, 0, stream>>>(Wq, WqkvT, DMODEL, DMODEL, lsQKV, 0);
    convT_kernel<<<dim3(12, 12, NLAYER), blk256, 0, stream>>>(Wk, WqkvT, DMODEL, DMODEL, lsQKV, DMODEL);
    convT_kernel<<<dim3(12, 12, NLAYER), blk256, 0, stream>>>(Wv, WqkvT, DMODEL, DMODEL, lsQKV, 2*DMODEL);
    convT_kernel<<<dim3(12, 12, NLAYER), blk256, 0, stream>>>(Wo, WoT, DMODEL, DMODEL, (size_t)DMODEL*DMODEL, 0);
    convT_kernel<<<dim3(12, 48, NLAYER), blk256, 0, stream>>>(W1, W1T, DMODEL, DFFN, (size_t)DMODEL*DFFN, 0);
    convT_kernel<<<dim3(48, 12, NLAYER), blk256, 0, stream>>>(W2, W2T, DFFN, DMODEL, (size_t)DFFN*DMODEL, 0);
    biascat_kernel<<<dim3(NLAYER), dim3(384), 0, stream>>>(bq, bk, bv, biasqkv);

    embed_ln_kernel<<<rowsGrid, blk256, 0, stream>>>(ids, we, pe, te, elg, elb, x, xb);

    for (int i = 0; i < NLAYER; ++i) {
        const ushort* WqkvT_i = WqkvT + (size_t)i * lsQKV;
        const ushort* WoT_i   = WoT + (size_t)i * DMODEL * DMODEL;
        const float*  Wb_i    = Wb  + (size_t)i * DMODEL * NH;
        const ushort* W1T_i   = W1T + (size_t)i * DMODEL * DFFN;
        const ushort* W2T_i   = W2T + (size_t)i * DFFN * DMODEL;

        gemm_mfma<ushort><<<gemmGrid_QKV, blk256, 0, stream>>>(xb, WqkvT_i, biasqkv + (size_t)i * DQKV,
                                                               qkvb, NROWS, DQKV, DMODEL, DMODEL, 0);
        beta_kernel<<<rowsGrid, blk256, 0, stream>>>(xb, Wb_i, mask, betab);
        // q/k l2norm + k*mask fused into scan staging; o overwrites q-section of qkvb
        scan_kernel<<<scanGrid, dim3(64), 0, stream>>>(qkvb, betab, mask,
                                                       dfast + i * NH, dslow + i * NH, qkvb);
        // Wo GEMM reads strided o (Astride = DQKV)
        gemm_mfma<ushort><<<gemmGrid_D, blk256, 0, stream>>>(qkvb, WoT_i, bo + i * DMODEL, ab,
                                                             NROWS, DMODEL, DMODEL, DQKV, 0);
        add_ln_kernel<<<rowsGrid, blk256, 0, stream>>>(x, xb, ab, l1g + i * DMODEL, l1b + i * DMODEL);

        // FFN UNCHUNKED (R11 win): h spans qkvb+ab (contiguous, exactly
        // 100,663,296 B; both dead). W2-out -> xb (dead after W1 GEMM);
        // add_ln_ip reads residual from xb and rewrites it.
        {
            ushort* hbuf = qkvb;   // 100.66 MB window (qkvb..ab end)
            gemm_mfma<ushort><<<gemmGrid_F1, blk256, 0, stream>>>(xb, W1T_i, b1 + i * DFFN, hbuf,
                                                                  NROWS, DFFN, DMODEL, DMODEL, 1);
            gemm_mfma<ushort><<<gemmGrid_F2, blk256, 0, stream>>>(hbuf, W2T_i, b2 + i * DMODEL, xb,
                                                                  NROWS, DMODEL, DFFN, DFFN, 0);
            add_ln_ip_kernel<<<rowsGrid, blk256, 0, stream>>>(x, xb, l2g + i * DMODEL, l2b + i * DMODEL);
        }
    }

    pool_kernel<<<dim3(BATCH), dim3(384), 0, stream>>>(x, mask, out);
}

// Round 14
// 2509.414 us; speedup vs baseline: 1.6147x; 1.1147x over previous
//
#include <hip/hip_runtime.h>
#include <cstdint>
#include <cstddef>
#include <cmath>

#define NLAYER 6
#define NH 12
#define DMODEL 384
#define DHEAD 32
#define DFFN 1536
#define BATCH 64
#define SEQ 512
#define NROWS (BATCH*SEQ)   // 32768
#define DQKV 1152           // fused q|k|v row length

typedef unsigned short ushort;
typedef __attribute__((ext_vector_type(8))) short bf16x8;   // 8 bf16 = 4 VGPRs
typedef __attribute__((ext_vector_type(4))) float f32x4;

// ---------------------------------------------------------------- utilities

__device__ inline float bf2f(ushort u) {
    union { unsigned int i; float f; } c; c.i = ((unsigned int)u) << 16; return c.f;
}
__device__ inline ushort f2bf(float f) {
    union { float f; unsigned int i; } c; c.f = f;
    unsigned int i = c.i;
    unsigned int lsb = (i >> 16) & 1u;
    i += 0x7fffu + lsb;          // round-to-nearest-even
    return (ushort)(i >> 16);
}

__device__ inline float wave_reduce_sum(float v) {
    #pragma unroll
    for (int m = 32; m >= 1; m >>= 1) v += __shfl_xor(v, m, 64);
    return v;
}

__device__ inline float sigmoidf(float x) { return 1.0f / (1.0f + expf(-x)); }

// fast exp-based tanh-gelu (R12 win): tanh(y) = 1 - 2/(e^{2y}+1); ~8 VALU ops.
__device__ inline float gelu_tanh(float x) {
    const float c = 0.7978845608028654f; // sqrt(2/pi)
    float y = c * (x + 0.044715f * x * x * x);
    float e = __expf(2.0f * y);
    float t = 1.0f - 2.0f * __builtin_amdgcn_rcpf(e + 1.0f);
    return 0.5f * x * (1.0f + t);
}

// async global->LDS, 16 bytes per lane; lds base must be wave-uniform
__device__ inline void async16(const ushort* g, ushort* l) {
    __builtin_amdgcn_global_load_lds(
        (const __attribute__((address_space(1))) unsigned int*)g,
        (__attribute__((address_space(3))) unsigned int*)l,
        16, 0, 0);
}

// dot of two float2[16] register arrays -> scalar (4 chains + tree)
__device__ inline float dot16(const float2* a, const float2* b) {
    float2 s0 = a[0]*b[0], s1 = a[1]*b[1], s2 = a[2]*b[2], s3 = a[3]*b[3];
    #pragma unroll
    for (int j = 4; j < 16; j += 4) {
        s0 += a[j]*b[j]; s1 += a[j+1]*b[j+1]; s2 += a[j+2]*b[j+2]; s3 += a[j+3]*b[j+3];
    }
    float2 s = (s0 + s1) + (s2 + s3);
    return s.x + s.y;
}

// ---------------------------------------------------------------- weight convert+transpose
__global__ __launch_bounds__(256)
void convT_kernel(const float* __restrict__ W, ushort* __restrict__ WT, int K, int N,
                  size_t lStride, int nOff)
{
    __shared__ float t[32][33];
    int k0 = blockIdx.x * 32, n0 = blockIdx.y * 32, L = blockIdx.z;
    const float* Wl = W + (size_t)L * K * N;
    ushort* WTl = WT + (size_t)L * lStride;
    int tx = threadIdx.x & 31, ty = threadIdx.x >> 5;   // 32 x 8
    #pragma unroll
    for (int i = 0; i < 4; ++i)
        t[ty + 8 * i][tx] = Wl[(size_t)(k0 + ty + 8 * i) * N + n0 + tx];
    __syncthreads();
    #pragma unroll
    for (int i = 0; i < 4; ++i)
        WTl[(size_t)(nOff + n0 + ty + 8 * i) * K + k0 + tx] = f2bf(t[tx][ty + 8 * i]);
}

// ---------------------------------------------------------------- fused qkv bias concat: [L][1152]
__global__ __launch_bounds__(384)
void biascat_kernel(const float* __restrict__ bq, const float* __restrict__ bk,
                    const float* __restrict__ bv, float* __restrict__ dst)
{
    int L = blockIdx.x, d = threadIdx.x;
    dst[(size_t)L * DQKV + d]             = bq[(size_t)L * DMODEL + d];
    dst[(size_t)L * DQKV + DMODEL + d]    = bk[(size_t)L * DMODEL + d];
    dst[(size_t)L * DQKV + 2*DMODEL + d]  = bv[(size_t)L * DMODEL + d];
}

// ---------------------------------------------------------------- embedding + LN (writes fp32 x and bf16 xb)
__global__ __launch_bounds__(256)
void embed_ln_kernel(const int* __restrict__ ids, const float* __restrict__ we,
                     const float* __restrict__ pe, const float* __restrict__ te,
                     const float* __restrict__ g, const float* __restrict__ bb,
                     float* __restrict__ x, ushort* __restrict__ xb)
{
    int row = blockIdx.x * 4 + (threadIdx.x >> 6);
    int lane = threadIdx.x & 63;
    int l = row & (SEQ - 1);
    int id = ids[row];
    float vals[6];
    float s = 0.f;
    #pragma unroll
    for (int t = 0; t < 6; ++t) {
        int d = lane + 64 * t;
        float v = we[(size_t)id * DMODEL + d] + pe[(size_t)l * DMODEL + d] + te[d];
        vals[t] = v; s += v;
    }
    s = wave_reduce_sum(s);
    float m = s * (1.0f / DMODEL);
    float s2 = 0.f;
    #pragma unroll
    for (int t = 0; t < 6; ++t) { float dd = vals[t] - m; s2 += dd * dd; }
    s2 = wave_reduce_sum(s2);
    float rs = rsqrtf(s2 * (1.0f / DMODEL) + 1e-12f);
    #pragma unroll
    for (int t = 0; t < 6; ++t) {
        int d = lane + 64 * t;
        float val = (vals[t] - m) * rs * g[d] + bb[d];
        x[(size_t)row * DMODEL + d] = val;
        xb[(size_t)row * DMODEL + d] = f2bf(val);
    }
}

// ---------------------------------------------------------------- residual add + LN (separate residual buffer r)
__global__ __launch_bounds__(256)
void add_ln_kernel(float* x, ushort* __restrict__ xb, const ushort* __restrict__ r,
                   const float* __restrict__ g, const float* __restrict__ bb)
{
    int row = blockIdx.x * 4 + (threadIdx.x >> 6);
    int lane = threadIdx.x & 63;
    float vals[6];
    float s = 0.f;
    #pragma unroll
    for (int t = 0; t < 6; ++t) {
        int d = lane + 64 * t;
        size_t idx = (size_t)row * DMODEL + d;
        float v = x[idx] + bf2f(r[idx]);
        vals[t] = v; s += v;
    }
    s = wave_reduce_sum(s);
    float m = s * (1.0f / DMODEL);
    float s2 = 0.f;
    #pragma unroll
    for (int t = 0; t < 6; ++t) { float dd = vals[t] - m; s2 += dd * dd; }
    s2 = wave_reduce_sum(s2);
    float rs = rsqrtf(s2 * (1.0f / DMODEL) + 1e-12f);
    #pragma unroll
    for (int t = 0; t < 6; ++t) {
        int d = lane + 64 * t;
        size_t idx = (size_t)row * DMODEL + d;
        float val = (vals[t] - m) * rs * g[d] + bb[d];
        x[idx] = val;
        xb[idx] = f2bf(val);
    }
}

// ---------------------------------------------------------------- residual add + LN, residual IN xb (in place)
__global__ __launch_bounds__(256)
void add_ln_ip_kernel(float* x, ushort* xb,
                      const float* __restrict__ g, const float* __restrict__ bb)
{
    int row = blockIdx.x * 4 + (threadIdx.x >> 6);
    int lane = threadIdx.x & 63;
    float vals[6];
    float s = 0.f;
    #pragma unroll
    for (int t = 0; t < 6; ++t) {
        int d = lane + 64 * t;
        size_t idx = (size_t)row * DMODEL + d;
        float v = x[idx] + bf2f(xb[idx]);
        vals[t] = v; s += v;
    }
    s = wave_reduce_sum(s);
    float m = s * (1.0f / DMODEL);
    float s2 = 0.f;
    #pragma unroll
    for (int t = 0; t < 6; ++t) { float dd = vals[t] - m; s2 += dd * dd; }
    s2 = wave_reduce_sum(s2);
    float rs = rsqrtf(s2 * (1.0f / DMODEL) + 1e-12f);
    #pragma unroll
    for (int t = 0; t < 6; ++t) {
        int d = lane + 64 * t;
        size_t idx = (size_t)row * DMODEL + d;
        float val = (vals[t] - m) * rs * g[d] + bb[d];
        x[idx] = val;
        xb[idx] = f2bf(val);
    }
}

// ---------------------------------------------------------------- bf16 MFMA GEMM, async-staged [verified R7]
// R12 win: XCD-chunked A-major block swizzle (identity fallback nwg%8!=0).
template<typename TC>
__global__ __launch_bounds__(256)
void gemm_mfma(const ushort* __restrict__ A, const ushort* __restrict__ WT,
               const float* __restrict__ bias, TC* __restrict__ C,
               int M, int N, int K, int Astride, int act)
{
    __shared__ __align__(16) ushort As[128 * 64];   // 16 KB
    __shared__ __align__(16) ushort Bs[128 * 64];   // 16 KB
    int tid = threadIdx.x;
    int lane = tid & 63, wv = tid >> 6;
    int waveM = wv >> 1, waveN = wv & 1;
    int lm = lane & 15, quad = lane >> 4;

    int bid = blockIdx.x + gridDim.x * blockIdx.y;
    int nwg = gridDim.x * gridDim.y;
    int w = bid;
    if ((nwg & 7) == 0) {
        int cpx = nwg >> 3;
        w = (bid & 7) * cpx + (bid >> 3);
    }
    int xt = w / gridDim.y;      // row-tile (A-major ordering)
    int yt = w % gridDim.y;      // col-tile
    int row0 = xt * 128, col0 = yt * 128;

    int srow = lane >> 3, sseg = lane & 7;          // staging: 8 rows x 8 segs

    f32x4 acc[4][4] = {};

    for (int k0 = 0; k0 < K; k0 += 64) {
        __syncthreads();
        #pragma unroll
        for (int i = 0; i < 4; ++i) {
            int r = wv * 32 + i * 8 + srow;
            int sg = sseg ^ (r & 7);
            async16(A  + (size_t)(row0 + r) * Astride + k0 + sg * 8, &As[(wv * 32 + i * 8) * 64]);
            async16(WT + (size_t)(col0 + r) * K + k0 + sg * 8, &Bs[(wv * 32 + i * 8) * 64]);
        }
        __syncthreads();

        #pragma unroll
        for (int ks = 0; ks < 2; ++ks) {
            int physA = ((ks * 4 + quad) ^ (lm & 7)) * 8;
            bf16x8 af[4], bf[4];
            #pragma unroll
            for (int mt = 0; mt < 4; ++mt)
                af[mt] = *(const bf16x8*)&As[(waveM * 64 + mt * 16 + lm) * 64 + physA];
            #pragma unroll
            for (int nt = 0; nt < 4; ++nt)
                bf[nt] = *(const bf16x8*)&Bs[(waveN * 64 + nt * 16 + lm) * 64 + physA];
            #pragma unroll
            for (int mt = 0; mt < 4; ++mt)
                #pragma unroll
                for (int nt = 0; nt < 4; ++nt)
                    acc[mt][nt] = __builtin_amdgcn_mfma_f32_16x16x32_bf16(af[mt], bf[nt], acc[mt][nt], 0, 0, 0);
        }
    }

    #pragma unroll
    for (int mt = 0; mt < 4; ++mt) {
        #pragma unroll
        for (int nt = 0; nt < 4; ++nt) {
            int col = col0 + waveN * 64 + nt * 16 + lm;
            float bv = bias[col];
            #pragma unroll
            for (int r = 0; r < 4; ++r) {
                int row = row0 + waveM * 64 + mt * 16 + quad * 4 + r;
                float val = acc[mt][nt][r] + bv;
                if (act == 1) val = gelu_tanh(gelu_tanh(val));
                if constexpr (sizeof(TC) == 2)
                    C[(size_t)row * N + col] = f2bf(val);
                else
                    C[(size_t)row * N + col] = val;
            }
        }
    }
}

// ---------------------------------------------------------------- beta: wave per row, coalesced bf16 x  [verified R7]
__global__ __launch_bounds__(256)
void beta_kernel(const ushort* __restrict__ xb, const float* __restrict__ Wb,
                 const float* __restrict__ mask, float* __restrict__ beta)
{
    int row = blockIdx.x * 4 + (threadIdx.x >> 6);
    int lane = threadIdx.x & 63;
    float xr[6];
    #pragma unroll
    for (int t = 0; t < 6; ++t) xr[t] = bf2f(xb[(size_t)row * DMODEL + lane + 64 * t]);
    float mine = 0.f;
    #pragma unroll
    for (int h = 0; h < NH; ++h) {
        float p = 0.f;
        #pragma unroll
        for (int t = 0; t < 6; ++t) p += xr[t] * Wb[(size_t)(lane + 64 * t) * NH + h];
        p = wave_reduce_sum(p);
        if (lane == h) mine = p;
    }
    if (lane < NH) beta[(size_t)row * NH + lane] = sigmoidf(mine) * mask[row];
}

// ---------------------------------------------------------------- delta-rule scan v12: state-split + deferred o-combine
// v11 (189 us) put the per-step o exchange (osb write -> lgkmcnt -> read ->
// global store) INSIDE the loop; at <1 wave/SIMD that serialized issue costs
// ~150-250 cyc/step. v12: per step only ONE fire-and-forget ds_write_b32 into
// osb2[t][lane]; after the 32-step loop, a bulk phase combines halves and
// issues all 32 global stores back-to-back (pipelined). Hazard: bulk stores
// touch rows t0..t0+31; prefetch reads rows >= t0+32. osb2 is wave-private
// (program-order waitcnts). All math identical to v11.
#define SCAN_T 32
#define SPAD 36
__global__ __launch_bounds__(64)
void scan_kernel(const ushort* __restrict__ qkv, const float* __restrict__ beta,
                 const float* __restrict__ mask,
                 const float* __restrict__ dfast, const float* __restrict__ dslow,
                 ushort* __restrict__ o)
{
    __shared__ __align__(16) float qs[SCAN_T][SPAD];
    __shared__ __align__(16) float ks[SCAN_T][SPAD];
    __shared__ __align__(16) float vs[SCAN_T][SPAD];
    __shared__ float bs[SCAN_T];
    __shared__ float osb2[SCAN_T][64];   // per-tile o halves (8 KB)

    int bh = blockIdx.x;               // 768 blocks, one (b,h) each
    int lane = threadIdx.x;
    int half = lane >> 5, n = lane & 31;
    int h16 = half << 4;
    int myb = bh / NH, myh = bh % NH;

    float g = sigmoidf(half ? dslow[myh] : dfast[myh]);
    float2 g2 = make_float2(g, g);
    float2 S[16];
    #pragma unroll
    for (int j = 0; j < 16; ++j) S[j] = make_float2(0.f, 0.f);

    // prefetch regs: lane (half,n) stages 16 elements (offset h16) of row t0+n
    uint4 pq[2], pk[2], pv[2];
    float pb, pmk;
    {
        size_t ra = (size_t)(myb * SEQ + n) * DQKV + myh * DHEAD + h16;
        pq[0] = *(const uint4*)(qkv + ra);     pq[1] = *(const uint4*)(qkv + ra + 8);
        pk[0] = *(const uint4*)(qkv + ra + DMODEL);     pk[1] = *(const uint4*)(qkv + ra + DMODEL + 8);
        pv[0] = *(const uint4*)(qkv + ra + 2*DMODEL);   pv[1] = *(const uint4*)(qkv + ra + 2*DMODEL + 8);
        pb  = beta[(size_t)(myb * SEQ + n) * NH + myh];
        pmk = mask[myb * SEQ + n];
    }

    for (int t0 = 0; t0 < SEQ; t0 += SCAN_T) {
        __syncthreads();
        // ---- stage tile: fused q/k l2norm (cross-half shfl once) + k*mask
        {
            ushort tq[16], tk[16], tv[16];
            *(uint4*)tq = pq[0]; *(uint4*)(tq + 8) = pq[1];
            *(uint4*)tk = pk[0]; *(uint4*)(tk + 8) = pk[1];
            *(uint4*)tv = pv[0]; *(uint4*)(tv + 8) = pv[1];
            float qv[16], kv[16];
            float sq = 0.f, sk = 0.f;
            #pragma unroll
            for (int j = 0; j < 16; ++j) {
                qv[j] = bf2f(tq[j]); sq += qv[j] * qv[j];
                kv[j] = bf2f(tk[j]); sk += kv[j] * kv[j];
            }
            sq += __shfl_xor(sq, 32, 64);   // partner lane = other half of same row
            sk += __shfl_xor(sk, 32, 64);
            float rq = 1.0f / (sqrtf(sq) + 1e-6f);
            float rk = pmk / (sqrtf(sk) + 1e-6f);
            #pragma unroll
            for (int s2 = 0; s2 < 4; ++s2) {
                float4 fq, fk, fv;
                fq.x = qv[s2*4+0]*rq; fq.y = qv[s2*4+1]*rq; fq.z = qv[s2*4+2]*rq; fq.w = qv[s2*4+3]*rq;
                fk.x = kv[s2*4+0]*rk; fk.y = kv[s2*4+1]*rk; fk.z = kv[s2*4+2]*rk; fk.w = kv[s2*4+3]*rk;
                fv.x = bf2f(tv[s2*4+0]); fv.y = bf2f(tv[s2*4+1]); fv.z = bf2f(tv[s2*4+2]); fv.w = bf2f(tv[s2*4+3]);
                *(float4*)&qs[n][h16 + s2*4] = fq;
                *(float4*)&ks[n][h16 + s2*4] = fk;
                *(float4*)&vs[n][h16 + s2*4] = fv;
            }
            if (!half) bs[n] = pb;
        }
        __syncthreads();

        // ---- prefetch next tile (vmcnt only; rows >= t0+32, o-writes < t0+32)
        if (t0 + SCAN_T < SEQ) {
            size_t ra = (size_t)(myb * SEQ + t0 + SCAN_T + n) * DQKV + myh * DHEAD + h16;
            pq[0] = *(const uint4*)(qkv + ra);     pq[1] = *(const uint4*)(qkv + ra + 8);
            pk[0] = *(const uint4*)(qkv + ra + DMODEL);     pk[1] = *(const uint4*)(qkv + ra + DMODEL + 8);
            pv[0] = *(const uint4*)(qkv + ra + 2*DMODEL);   pv[1] = *(const uint4*)(qkv + ra + 2*DMODEL + 8);
            pb  = beta[(size_t)(myb * SEQ + t0 + SCAN_T + n) * NH + myh];
            pmk = mask[myb * SEQ + t0 + SCAN_T + n];
        }

        #pragma unroll 4
        for (int t = 0; t < SCAN_T; ++t) {
            float2 kt[16], qt[16];
            #pragma unroll
            for (int s2 = 0; s2 < 8; ++s2) {
                *(float4*)&kt[s2 * 2] = *(const float4*)&ks[t][s2 * 4];   // full row: broadcast
                *(float4*)&qt[s2 * 2] = *(const float4*)&qs[t][s2 * 4];
            }
            float vt = vs[t][n], bt = bs[t];

            float p = dot16(kt, S);
            float c = bt * (vt - p);
            float2 c2 = make_float2(c, c);

            float2 o0 = make_float2(0.f, 0.f), o1 = o0, o2 = o0, o3 = o0;
            #pragma unroll
            for (int j = 0; j < 16; j += 4) {
                S[j]   = g2 * S[j]   + kt[j]   * c2;
                S[j+1] = g2 * S[j+1] + kt[j+1] * c2;
                S[j+2] = g2 * S[j+2] + kt[j+2] * c2;
                S[j+3] = g2 * S[j+3] + kt[j+3] * c2;
                o0 += qt[j]   * S[j];
                o1 += qt[j+1] * S[j+1];
                o2 += qt[j+2] * S[j+2];
                o3 += qt[j+3] * S[j+3];
            }
            float2 ov = (o0 + o1) + (o2 + o3);
            osb2[t][lane] = ov.x + ov.y;     // fire-and-forget; combined in bulk phase
        }

        // ---- bulk o-combine + store (pipelined; off the recurrence path)
        // lane (half,n): handles t = 2*tt + half; 32 lanes with same t write
        // 64B contiguous rows.
        #pragma unroll
        for (int tt = 0; tt < SCAN_T / 2; ++tt) {
            int t = tt * 2 + half;
            float osum = osb2[t][n] + osb2[t][n + 32];
            o[((size_t)(myb * SEQ + t0 + t)) * DQKV + myh * DHEAD + n] = f2bf(0.5f * osum);
        }
    }
}

// ---------------------------------------------------------------- masked mean-pool + l2 normalize
__global__ __launch_bounds__(384)
void pool_kernel(const float* __restrict__ x, const float* __restrict__ mask,
                 float* __restrict__ out)
{
    int b = blockIdx.x;
    int d = threadIdx.x;
    float acc = 0.f, msum = 0.f;
    for (int l = 0; l < SEQ; ++l) {
        float mk = mask[b * SEQ + l];
        acc += x[((size_t)b * SEQ + l) * DMODEL + d] * mk;
        msum += mk;
    }
    float emb = acc / fmaxf(msum, 1e-9f);
    __shared__ float red[6];
    float ss = wave_reduce_sum(emb * emb);
    int wvi = d >> 6, ln = d & 63;
    if (ln == 0) red[wvi] = ss;
    __syncthreads();
    float tot = 0.f;
    #pragma unroll
    for (int i = 0; i < 6; ++i) tot += red[i];
    float nrm = fmaxf(sqrtf(tot), 1e-12f);
    out[(size_t)b * DMODEL + d] = emb / nrm;
}

// ---------------------------------------------------------------- launch

extern "C" void kernel_launch(void* const* d_in, const int* in_sizes, int n_in,
                              void* d_out, int out_size, void* d_ws, size_t ws_size,
                              hipStream_t stream)
{
    const int*   ids   = (const int*)d_in[0];
    const float* mask  = (const float*)d_in[1];
    const float* we    = (const float*)d_in[2];
    const float* pe    = (const float*)d_in[3];
    const float* te    = (const float*)d_in[4];
    const float* elg   = (const float*)d_in[5];
    const float* elb   = (const float*)d_in[6];
    const float* Wq    = (const float*)d_in[7];
    const float* bq    = (const float*)d_in[8];
    const float* Wk    = (const float*)d_in[9];
    const float* bk    = (const float*)d_in[10];
    const float* Wv    = (const float*)d_in[11];
    const float* bv    = (const float*)d_in[12];
    const float* Wb    = (const float*)d_in[13];
    const float* dfast = (const float*)d_in[14];
    const float* dslow = (const float*)d_in[15];
    const float* Wo    = (const float*)d_in[16];
    const float* bo    = (const float*)d_in[17];
    const float* l1g   = (const float*)d_in[18];
    const float* l1b   = (const float*)d_in[19];
    const float* W1    = (const float*)d_in[20];
    const float* b1    = (const float*)d_in[21];
    const float* W2    = (const float*)d_in[22];
    const float* b2    = (const float*)d_in[23];
    const float* l2g   = (const float*)d_in[24];
    const float* l2b   = (const float*)d_in[25];
    float* out = (float*)d_out;

    // ---- workspace: 199.0 MB total (proven ceiling 202.9 MB, R4) ----
    const size_t RD = (size_t)NROWS * DMODEL;    // 12,582,912 elements
    float* x      = (float*)d_ws;                      // 50.33 MB
    float* betab  = x + RD;                            //  1.57 MB
    ushort* xb    = (ushort*)(betab + (size_t)NROWS * NH);   // 25.17 MB
    ushort* qkvb  = xb + RD;                           // 75.50 MB  [row][1152]
    ushort* ab    = qkvb + (size_t)NROWS * DQKV;       // 25.17 MB (attn out; FFN: tail of h)
    ushort* WqkvT = ab + RD;                           //  5.31 MB [L][1152][384]
    ushort* WoT   = WqkvT + (size_t)NLAYER * DQKV * DMODEL;  // 1.77 MB
    ushort* W1T   = WoT + (size_t)NLAYER * DMODEL * DMODEL;  // 7.08 MB [L][1536][384]
    ushort* W2T   = W1T + (size_t)NLAYER * DMODEL * DFFN;    // 7.08 MB [L][384][1536]
    float* biasqkv = (float*)(W2T + (size_t)NLAYER * DFFN * DMODEL); // 27 KB

    dim3 blk256(256);
    dim3 rowsGrid(NROWS / 4);
    dim3 gemmGrid_QKV(NROWS / 128, DQKV / 128);      // (256, 9)
    dim3 gemmGrid_D(NROWS / 128, DMODEL / 128);      // (256, 3)
    dim3 gemmGrid_F1(NROWS / 128, DFFN / 128);       // (256, 12) unchunked
    dim3 gemmGrid_F2(NROWS / 128, DMODEL / 128);     // (256, 3)  unchunked
    dim3 scanGrid(BATCH * NH);                       // 768 single-wave blocks (state-split)

    const size_t lsQKV = (size_t)DQKV * DMODEL;
    convT_kernel<<<dim3(12, 12, NLAYER), blk256, 0, stream>>>(Wq, WqkvT, DMODEL, DMODEL, lsQKV, 0);
    convT_kernel<<<dim3(12, 12, NLAYER), blk256, 0, stream>>>(Wk, WqkvT, DMODEL, DMODEL, lsQKV, DMODEL);
    convT_kernel<<<dim3(12, 12, NLAYER), blk256, 0, stream>>>(Wv, WqkvT, DMODEL, DMODEL, lsQKV, 2*DMODEL);
    convT_kernel<<<dim3(12, 12, NLAYER), blk256, 0, stream>>>(Wo, WoT, DMODEL, DMODEL, (size_t)DMODEL*DMODEL, 0);
    convT_kernel<<<dim3(12, 48, NLAYER), blk256, 0, stream>>>(W1, W1T, DMODEL, DFFN, (size_t)DMODEL*DFFN, 0);
    convT_kernel<<<dim3(48, 12, NLAYER), blk256, 0, stream>>>(W2, W2T, DFFN, DMODEL, (size_t)DFFN*DMODEL, 0);
    biascat_kernel<<<dim3(NLAYER), dim3(384), 0, stream>>>(bq, bk, bv, biasqkv);

    embed_ln_kernel<<<rowsGrid, blk256, 0, stream>>>(ids, we, pe, te, elg, elb, x, xb);

    for (int i = 0; i < NLAYER; ++i) {
        const ushort* WqkvT_i = WqkvT + (size_t)i * lsQKV;
        const ushort* WoT_i   = WoT + (size_t)i * DMODEL * DMODEL;
        const float*  Wb_i    = Wb  + (size_t)i * DMODEL * NH;
        const ushort* W1T_i   = W1T + (size_t)i * DMODEL * DFFN;
        const ushort* W2T_i   = W2T + (size_t)i * DFFN * DMODEL;

        gemm_mfma<ushort><<<gemmGrid_QKV, blk256, 0, stream>>>(xb, WqkvT_i, biasqkv + (size_t)i * DQKV,
                                                               qkvb, NROWS, DQKV, DMODEL, DMODEL, 0);
        beta_kernel<<<rowsGrid, blk256, 0, stream>>>(xb, Wb_i, mask, betab);
        // q/k l2norm + k*mask fused into scan staging; o overwrites q-section of qkvb
        scan_kernel<<<scanGrid, dim3(64), 0, stream>>>(qkvb, betab, mask,
                                                       dfast + i * NH, dslow + i * NH, qkvb);
        // Wo GEMM reads strided o (Astride = DQKV)
        gemm_mfma<ushort><<<gemmGrid_D, blk256, 0, stream>>>(qkvb, WoT_i, bo + i * DMODEL, ab,
                                                             NROWS, DMODEL, DMODEL, DQKV, 0);
        add_ln_kernel<<<rowsGrid, blk256, 0, stream>>>(x, xb, ab, l1g + i * DMODEL, l1b + i * DMODEL);

        // FFN UNCHUNKED (R11 win): h spans qkvb+ab (contiguous, exactly
        // 100,663,296 B; both dead). W2-out -> xb (dead after W1 GEMM);
        // add_ln_ip reads residual from xb and rewrites it.
        {
            ushort* hbuf = qkvb;   // 100.66 MB window (qkvb..ab end)
            gemm_mfma<ushort><<<gemmGrid_F1, blk256, 0, stream>>>(xb, W1T_i, b1 + i * DFFN, hbuf,
                                                                  NROWS, DFFN, DMODEL, DMODEL, 1);
            gemm_mfma<ushort><<<gemmGrid_F2, blk256, 0, stream>>>(hbuf, W2T_i, b2 + i * DMODEL, xb,
                                                                  NROWS, DMODEL, DFFN, DFFN, 0);
            add_ln_ip_kernel<<<rowsGrid, blk256, 0, stream>>>(x, xb, l2g + i * DMODEL, l2b + i * DMODEL);
        }
    }

    pool_kernel<<<dim3(BATCH), dim3(384), 0, stream>>>(x, mask, out);
}